// Round 12
// baseline (898.487 us; speedup 1.0000x reference)
//
#include <hip/hip_runtime.h>

typedef unsigned short u16;
typedef unsigned int   u32;
typedef __bf16 bf16;
typedef bf16  bf16x8 __attribute__((ext_vector_type(8)));
typedef u16   u16x8  __attribute__((ext_vector_type(8)));
typedef u32   u32x4  __attribute__((ext_vector_type(4)));
typedef float f32x4  __attribute__((ext_vector_type(4)));
typedef float f32x16 __attribute__((ext_vector_type(16)));

__device__ __forceinline__ u16 f2bf(float f) {
  u32 u = __builtin_bit_cast(u32, f);
  u32 r = u + 0x7fffu + ((u >> 16) & 1u);
  return (u16)(r >> 16);
}

__device__ __forceinline__ u32 cvtpk(float lo, float hi) {
  u32 r;
  asm("v_cvt_pk_bf16_f32 %0, %1, %2" : "=v"(r) : "v"(lo), "v"(hi));
  return r;
}

__device__ __forceinline__ bf16x8 ldb8(const u16* p) {
  return __builtin_bit_cast(bf16x8, *reinterpret_cast<const u16x8*>(p));
}

__device__ __forceinline__ f32x4 mfma16(bf16x8 a, bf16x8 b, f32x4 c) {
  return __builtin_amdgcn_mfma_f32_16x16x32_bf16(a, b, c, 0, 0, 0);
}

__device__ __forceinline__ f32x16 mfma32(bf16x8 a, bf16x8 b, f32x16 c) {
  return __builtin_amdgcn_mfma_f32_32x32x16_bf16(a, b, c, 0, 0, 0);
}

__device__ __forceinline__ void gl_lds16(const void* g, void* l) {
  __builtin_amdgcn_global_load_lds(
      (const __attribute__((address_space(1))) void*)g,
      (__attribute__((address_space(3))) void*)l, 16, 0, 0);
}

// unswizzled staging (gemm_out)
__device__ __forceinline__ void stage128x64(const u16* gbase, u16* lds, int tid) {
#pragma unroll
  for (int rd = 0; rd < 4; rd++) {
    int o = rd * 4096 + tid * 16;
    int row = o >> 7, colb = o & 127;
    gl_lds16((const char*)gbase + (size_t)row * 2048 + colb, (char*)lds + o);
  }
}
__device__ __forceinline__ void stage64x64(const u16* gbase, u16* lds, int tid) {
#pragma unroll
  for (int rd = 0; rd < 2; rd++) {
    int o = rd * 4096 + tid * 16;
    int row = o >> 7, colb = o & 127;
    gl_lds16((const char*)gbase + (size_t)row * 2048 + colb, (char*)lds + o);
  }
}

// swizzled staging for the 8-wave GEMM: LDS linear dest, pre-swizzled global src.
__device__ __forceinline__ void stage_swz(const u16* g, u16* lds, int tid, int rd) {
  int o = rd * 8192 + tid * 16;
  int row = o >> 7;
  int slot = (tid & 7) ^ (row & 7);
  gl_lds16((const char*)g + (size_t)row * 2048 + slot * 16, (char*)lds + o);
}

// Fragment-linear layouts (per bh: 131072 u16 = 256 KB):
__device__ __forceinline__ size_t qk_frag_addr(int bh, int t, int d) {
  return (size_t)bh * 131072 + (size_t)(t >> 5) * 2048 +
         (size_t)((d >> 4) * 512 + ((d >> 3) & 1) * 256 + (t & 31) * 8 + (d & 7));
}
__device__ __forceinline__ size_t v_frag_addr(int bh, int t, int d) {
  return (size_t)bh * 131072 + (size_t)(t >> 5) * 2048 +
         (size_t)((d >> 5) * 1024 + ((t >> 4) & 1) * 512 +
                  (((t >> 3) & 1) * 32 + (d & 31)) * 8 + (t & 7));
}

// ---------------- fp32 -> bf16 conversion ----------------
__global__ void cvt_bf16(const float* __restrict__ in, u16* __restrict__ out, int n4) {
  int stride = gridDim.x * blockDim.x;
  for (int i = blockIdx.x * blockDim.x + threadIdx.x; i < n4; i += stride) {
    float4 f = reinterpret_cast<const float4*>(in)[i];
    ushort4 o;
    o.x = f2bf(f.x); o.y = f2bf(f.y); o.z = f2bf(f.z); o.w = f2bf(f.w);
    reinterpret_cast<ushort4*>(out)[i] = o;
  }
}

// ---------------- RoPE tables: [2048][32] cos/sin ----------------
__global__ void rope_tab(float* __restrict__ ct, float* __restrict__ st) {
  int idx = blockIdx.x * 256 + threadIdx.x;
  int t = idx >> 5, i = idx & 31;
  float theta = exp2f(-(float)i * 0.4152410118609203f);
  float ang = (float)t * theta;
  ct[idx] = cosf(ang);
  st[idx] = sinf(ang);
}

// ---------------- QKV GEMM: 256x128 tile, 8 waves, 3-buffer counted-vmcnt -------
// T2 swizzle + T3 phases + T4 counted vmcnt(6) + T5 setprio.
__global__ __launch_bounds__(512) void gemm_qkv(
    const u16* __restrict__ xb, const u16* __restrict__ wb,
    u16* __restrict__ qfb, u16* __restrict__ kfb, u16* __restrict__ vfb,
    const float* __restrict__ cost, const float* __restrict__ sint) {
  __shared__ u16 As[3][256 * 64];   // 96 KB
  __shared__ u16 Bs[3][128 * 64];   // 48 KB
  int tid = threadIdx.x, lane = tid & 63, wid = tid >> 6;
  int wm = wid >> 1, wn = wid & 1;
  int lr = lane & 15, lk = lane >> 4;
  int m0 = blockIdx.y * 256, n0 = blockIdx.x * 128;
  const u16* gA = xb + (size_t)m0 * 1024;
  const u16* gB = wb + (size_t)n0 * 1024;
  int swz = lr & 7;

  f32x4 acc[4][4] = {};

  // prologue: stage tiles 0 and 1
#pragma unroll
  for (int rd = 0; rd < 4; rd++) stage_swz(gA, As[0], tid, rd);
#pragma unroll
  for (int rd = 0; rd < 2; rd++) stage_swz(gB, Bs[0], tid, rd);
#pragma unroll
  for (int rd = 0; rd < 4; rd++) stage_swz(gA + 64, As[1], tid, rd);
#pragma unroll
  for (int rd = 0; rd < 2; rd++) stage_swz(gB + 64, Bs[1], tid, rd);
  asm volatile("s_waitcnt vmcnt(6)" ::: "memory");   // tile 0 landed
  __builtin_amdgcn_s_barrier();

#pragma unroll 1
  for (int t = 0; t < 16; t++) {
    const u16* Ac = As[t % 3];
    const u16* Bc = Bs[t % 3];
    u16* An = As[(t + 2) % 3];
    u16* Bn = Bs[(t + 2) % 3];
    const u16* gAn = gA + (t + 2) * 64;
    const u16* gBn = gB + (t + 2) * 64;
    bool pf = (t <= 13);
    bf16x8 af[4], bfr[4];

    // ---- phase 0 (kk = 0) ----
#pragma unroll
    for (int mr = 0; mr < 4; mr++)
      af[mr] = ldb8(&Ac[(wm * 64 + mr * 16 + lr) * 64 + ((lk ^ swz) * 8)]);
#pragma unroll
    for (int nr = 0; nr < 4; nr++)
      bfr[nr] = ldb8(&Bc[(wn * 64 + nr * 16 + lr) * 64 + ((lk ^ swz) * 8)]);
    if (pf) {
      stage_swz(gAn, An, tid, 0);
      stage_swz(gAn, An, tid, 1);
      stage_swz(gBn, Bn, tid, 0);
    }
    __builtin_amdgcn_s_setprio(1);
#pragma unroll
    for (int mr = 0; mr < 4; mr++)
#pragma unroll
      for (int nr = 0; nr < 4; nr++)
        acc[mr][nr] = mfma16(af[mr], bfr[nr], acc[mr][nr]);
    __builtin_amdgcn_s_setprio(0);
    __builtin_amdgcn_s_barrier();

    // ---- phase 1 (kk = 1) ----
#pragma unroll
    for (int mr = 0; mr < 4; mr++)
      af[mr] = ldb8(&Ac[(wm * 64 + mr * 16 + lr) * 64 + (((lk + 4) ^ swz) * 8)]);
#pragma unroll
    for (int nr = 0; nr < 4; nr++)
      bfr[nr] = ldb8(&Bc[(wn * 64 + nr * 16 + lr) * 64 + (((lk + 4) ^ swz) * 8)]);
    if (pf) {
      stage_swz(gAn, An, tid, 2);
      stage_swz(gAn, An, tid, 3);
      stage_swz(gBn, Bn, tid, 1);
    }
    __builtin_amdgcn_s_setprio(1);
#pragma unroll
    for (int mr = 0; mr < 4; mr++)
#pragma unroll
      for (int nr = 0; nr < 4; nr++)
        acc[mr][nr] = mfma16(af[mr], bfr[nr], acc[mr][nr]);
    __builtin_amdgcn_s_setprio(0);
    // counted drain: ensure tile t+1's loads landed before crossing the barrier.
    // outstanding here: t+1's 6 + (t<=13 ? t+2's 6 : 0)
    if (t < 14) {
      asm volatile("s_waitcnt vmcnt(6)" ::: "memory");
    } else if (t == 14) {
      asm volatile("s_waitcnt vmcnt(0)" ::: "memory");
    }
    __builtin_amdgcn_s_barrier();
  }

  const float CQ = 0.18033688011112042f;
  int sec = n0 >> 10;

  if (sec < 2) {
    u16* buf = (sec == 0) ? qfb : kfb;
    float scale = (sec == 0) ? CQ : 1.0f;
#pragma unroll
    for (int nr = 0; nr < 4; nr++) {
      int col = n0 + wn * 64 + nr * 16 + lr;
      int cc = col & 1023;
      int h = cc >> 6, d = cc & 63;
#pragma unroll
      for (int mr = 0; mr < 4; mr++) {
        int Mb = m0 + wm * 64 + mr * 16 + lk * 4;
#pragma unroll
        for (int r = 0; r < 4; r++) {
          int M = Mb + r;
          int b = M >> 11, tt = M & 2047;
          float val = acc[mr][nr][r];
          float par = __shfl_xor(val, 1);
          float c_ = cost[tt * 32 + (d >> 1)];
          float s_ = sint[tt * 32 + (d >> 1)];
          float res = (d & 1) ? (val * c_ + par * s_) : (val * c_ - par * s_);
          buf[qk_frag_addr(b * 16 + h, tt, d)] = f2bf(res * scale);
        }
      }
    }
  } else {
#pragma unroll
    for (int nr = 0; nr < 4; nr++) {
      int col = n0 + wn * 64 + nr * 16 + lr;
      int cc = col & 1023;
      int h = cc >> 6, d = cc & 63;
#pragma unroll
      for (int mr = 0; mr < 4; mr++) {
        int Mb = m0 + wm * 64 + mr * 16 + lk * 4;
        int b = Mb >> 11, tt = Mb & 2047;
        ushort4 pk;
        pk.x = f2bf(acc[mr][nr][0]); pk.y = f2bf(acc[mr][nr][1]);
        pk.z = f2bf(acc[mr][nr][2]); pk.w = f2bf(acc[mr][nr][3]);
        *reinterpret_cast<ushort4*>(&vfb[v_frag_addr(b * 16 + h, tt, d)]) = pk;
      }
    }
  }
}

// ---------------- Flash attention: 4-wave KV-split, shfl pack + MFMA row-sum -----
__device__ __forceinline__ void attn_step(
    const u16* __restrict__ kfb, const u16* __restrict__ vfb,
    const bf16x8* qf, bf16x8 ones, int kt, int qt, int qrow,
    int lane, int hi,
    f32x16& o0, f32x16& o1, f32x16& lsum, float& m_) {
  const u16* ktb = kfb + (size_t)kt * 2048;
  const u16* vtb = vfb + (size_t)kt * 2048;
  bf16x8 vf00 = ldb8(vtb + lane * 8);
  bf16x8 vf01 = ldb8(vtb + 512 + lane * 8);
  bf16x8 vf10 = ldb8(vtb + 1024 + lane * 8);
  bf16x8 vf11 = ldb8(vtb + 1536 + lane * 8);

  f32x16 sT = {};
#pragma unroll
  for (int s = 0; s < 4; s++) {
    bf16x8 kf = ldb8(ktb + s * 512 + lane * 8);
    sT = mfma32(kf, qf[s], sT);
  }
  if (kt == qt) {   // causal mask on diagonal tile
    int k0 = kt * 32;
#pragma unroll
    for (int r = 0; r < 16; r++) {
      int kvg = k0 + (r & 3) + 8 * (r >> 2) + 4 * hi;
      if (kvg > qrow) sT[r] = -3.0e38f;
    }
  }
  // row max: max3-fusable tree + 1 cross-half shfl
  float a0 = fmaxf(fmaxf(sT[0], sT[1]),  sT[2]);
  float a1 = fmaxf(fmaxf(sT[3], sT[4]),  sT[5]);
  float a2 = fmaxf(fmaxf(sT[6], sT[7]),  sT[8]);
  float a3 = fmaxf(fmaxf(sT[9], sT[10]), sT[11]);
  float a4 = fmaxf(fmaxf(sT[12], sT[13]), sT[14]);
  float b0 = fmaxf(fmaxf(a0, a1), a2);
  float b1 = fmaxf(fmaxf(a3, a4), sT[15]);
  float pm = fmaxf(b0, b1);
  pm = fmaxf(pm, __shfl_xor(pm, 32));

  if (__any(pm > m_ + 8.0f)) {    // defer-max
    float mn = fmaxf(m_, pm);
    float corr = exp2f(m_ - mn);
    lsum[0] *= corr;              // only [0] is ever read
    o0 *= corr; o1 *= corr;
    m_ = mn;
  }

  float p[16];
#pragma unroll
  for (int r = 0; r < 16; r++) p[r] = exp2f(sT[r] - m_);

  // pack P to bf16 pairs; exchange across lane halves (proven form)
  u32 c0 = cvtpk(p[0], p[1]),   c1 = cvtpk(p[2], p[3]);
  u32 c2 = cvtpk(p[4], p[5]),   c3 = cvtpk(p[6], p[7]);
  u32 c4 = cvtpk(p[8], p[9]),   c5 = cvtpk(p[10], p[11]);
  u32 c6 = cvtpk(p[12], p[13]), c7 = cvtpk(p[14], p[15]);
  u32 x0 = __shfl_xor((int)c0, 32), x1 = __shfl_xor((int)c1, 32);
  u32 x2 = __shfl_xor((int)c2, 32), x3 = __shfl_xor((int)c3, 32);
  u32 x4 = __shfl_xor((int)c4, 32), x5 = __shfl_xor((int)c5, 32);
  u32 x6 = __shfl_xor((int)c6, 32), x7 = __shfl_xor((int)c7, 32);
  u32x4 w0 = { hi ? x2 : c0, hi ? x3 : c1, hi ? c2 : x0, hi ? c3 : x1 };
  u32x4 w1 = { hi ? x6 : c4, hi ? x7 : c5, hi ? c6 : x4, hi ? c7 : x5 };
  bf16x8 pf0 = __builtin_bit_cast(bf16x8, w0);
  bf16x8 pf1 = __builtin_bit_cast(bf16x8, w1);

  // row-sum via MFMA (all-ones A)
  lsum = mfma32(ones, pf0, lsum);
  lsum = mfma32(ones, pf1, lsum);

  o0 = mfma32(vf00, pf0, o0);
  o0 = mfma32(vf01, pf1, o0);
  o1 = mfma32(vf10, pf0, o1);
  o1 = mfma32(vf11, pf1, o1);
}

__device__ __forceinline__ void stash_state(
    float* o_l, float* ml, int lane,
    const f32x16& o0, const f32x16& o1, float m_, float l_) {
#pragma unroll
  for (int r = 0; r < 16; r++) {
    o_l[r * 64 + lane]        = o0[r];
    o_l[(16 + r) * 64 + lane] = o1[r];
  }
  ml[lane]      = m_;
  ml[64 + lane] = l_;
}

__device__ __forceinline__ void merge_state(
    const float* o_l, const float* ml, int lane,
    f32x16& o0, f32x16& o1, float& m_, float& l_) {
  float me = ml[lane], le = ml[64 + lane];
  float mn = fmaxf(m_, me);
  float sc = exp2f(m_ - mn), se = exp2f(me - mn);
  l_ = l_ * sc + le * se;
#pragma unroll
  for (int r = 0; r < 16; r++) {
    o0[r] = o0[r] * sc + o_l[r * 64 + lane] * se;
    o1[r] = o1[r] * sc + o_l[(16 + r) * 64 + lane] * se;
  }
  m_ = mn;
}

__device__ __forceinline__ void attn_half(
    const u16* __restrict__ qfb, const u16* __restrict__ kfb,
    const u16* __restrict__ vfb, u16* __restrict__ og,
    float* o_lds, float* ml_lds, bf16x8 ones,
    int qt, int kt0, int w, int lane, int l31, int hi,
    size_t outbase) {
  int qrow = qt * 32 + l31;
  bf16x8 qf[4];
#pragma unroll
  for (int s = 0; s < 4; s++)
    qf[s] = ldb8(qfb + (size_t)qt * 2048 + s * 512 + lane * 8);

  f32x16 o0 = {}, o1 = {}, lsum = {};
  float m_ = -3.0e38f;

#pragma unroll 1
  for (int kt = kt0; kt <= qt; kt += 4)
    attn_step(kfb, vfb, qf, ones, kt, qt, qrow, lane, hi, o0, o1, lsum, m_);

  float l_ = lsum[0];

  if (w >= 2) stash_state(o_lds + (w - 2) * 2048, ml_lds + (w - 2) * 128, lane, o0, o1, m_, l_);
  __syncthreads();
  if (w < 2)  merge_state(o_lds + w * 2048, ml_lds + w * 128, lane, o0, o1, m_, l_);
  __syncthreads();
  if (w == 1) stash_state(o_lds, ml_lds, lane, o0, o1, m_, l_);
  __syncthreads();
  if (w == 0) {
    merge_state(o_lds, ml_lds, lane, o0, o1, m_, l_);
    float inv = 1.0f / l_;
    size_t base = outbase + (size_t)qrow * 1024;
#pragma unroll
    for (int db = 0; db < 2; db++) {
      f32x16 oo = db ? o1 : o0;
#pragma unroll
      for (int r = 0; r < 16; r += 2) {
        int d = db * 32 + (r & 3) + 8 * (r >> 2) + 4 * hi;
        u32 pk_ = cvtpk(oo[r] * inv, oo[r + 1] * inv);
        *reinterpret_cast<u32*>(&og[base + d]) = pk_;
      }
    }
  }
  __syncthreads();
}

__global__ __launch_bounds__(256, 8) void attn_fwd(
    const u16* __restrict__ qg, const u16* __restrict__ kg,
    const u16* __restrict__ vg, u16* __restrict__ og) {
  __shared__ float o_lds[2 * 32 * 64];
  __shared__ float ml_lds[2 * 2 * 64];
  int tid = threadIdx.x, lane = tid & 63, w = tid >> 6;
  int l31 = lane & 31, hi = lane >> 5;
  int blk = blockIdx.x;
  int bh = blk & 63, i = blk >> 6;
  const u16* qfb = qg + (size_t)bh * 131072;
  const u16* kfb = kg + (size_t)bh * 131072;
  const u16* vfb = vg + (size_t)bh * 131072;
  int hh = bh & 15, b = bh >> 4;
  size_t outbase = (size_t)b * 2048 * 1024 + hh * 64;

  u16x8 ov = {0x3F80, 0x3F80, 0x3F80, 0x3F80, 0x3F80, 0x3F80, 0x3F80, 0x3F80};
  bf16x8 ones = __builtin_bit_cast(bf16x8, ov);

  attn_half(qfb, kfb, vfb, og, o_lds, ml_lds, ones, i, w, w, lane, l31, hi, outbase);
  attn_half(qfb, kfb, vfb, og, o_lds, ml_lds, ones, 63 - i, (w - i - 1) & 3, w, lane, l31, hi, outbase);
}

// ---------------- Output GEMM (8192x1024x1024), 128x64 tiles, fp32 out ----------
__global__ __launch_bounds__(256) void gemm_out(
    const u16* __restrict__ ab, const u16* __restrict__ wb, float* __restrict__ out) {
  __shared__ u16 As[128 * 64];
  __shared__ u16 Bs[64 * 64];
  int tid = threadIdx.x, lane = tid & 63, w = tid >> 6;
  int wm = w >> 1, wn = w & 1;
  int lr = lane & 15, lk = lane >> 4;
  int m0 = blockIdx.y * 128, n0 = blockIdx.x * 64;

  f32x4 acc[4][2] = {};

  for (int k0 = 0; k0 < 1024; k0 += 64) {
    stage128x64(ab + (size_t)m0 * 1024 + k0, As, tid);
    stage64x64(wb + (size_t)n0 * 1024 + k0, Bs, tid);
    asm volatile("s_waitcnt vmcnt(0)" ::: "memory");
    __syncthreads();
#pragma unroll
    for (int kk = 0; kk < 2; kk++) {
      bf16x8 af[4], bfr[2];
#pragma unroll
      for (int mt = 0; mt < 4; mt++) af[mt]  = ldb8(&As[(64 * wm + 16 * mt + lr) * 64 + lk * 8 + 32 * kk]);
#pragma unroll
      for (int nt = 0; nt < 2; nt++) bfr[nt] = ldb8(&Bs[(32 * wn + 16 * nt + lr) * 64 + lk * 8 + 32 * kk]);
#pragma unroll
      for (int mt = 0; mt < 4; mt++)
#pragma unroll
        for (int nt = 0; nt < 2; nt++)
          acc[mt][nt] = mfma16(af[mt], bfr[nt], acc[mt][nt]);
    }
    __syncthreads();
  }

#pragma unroll
  for (int nt = 0; nt < 2; nt++) {
    int col = n0 + 32 * wn + 16 * nt + lr;
#pragma unroll
    for (int mt = 0; mt < 4; mt++) {
      int Mb = m0 + 64 * wm + 16 * mt + lk * 4;
#pragma unroll
      for (int r = 0; r < 4; r++) {
        out[(size_t)(Mb + r) * 1024 + col] = acc[mt][nt][r];
      }
    }
  }
}

// ---------------- launcher ----------------
extern "C" void kernel_launch(void* const* d_in, const int* in_sizes, int n_in,
                              void* d_out, int out_size, void* d_ws, size_t ws_size,
                              hipStream_t stream) {
  const float* x    = (const float*)d_in[0];
  const float* Wqkv = (const float*)d_in[2];
  const float* Wout = (const float*)d_in[3];
  float* out = (float*)d_out;
  char* ws = (char*)d_ws;

  u16* x_bf    = (u16*)(ws + 0);            // 16 MB
  u16* wqkv_bf = (u16*)(ws + 16777216);     // 6 MB
  u16* wout_bf = (u16*)(ws + 23068672);     // 2 MB
  u16* qf_buf  = (u16*)(ws + 25165824);     // 16 MB  fragment-linear Q (prescaled)
  u16* kf_buf  = (u16*)(ws + 41943040);     // 16 MB  fragment-linear K
  u16* vf_buf  = (u16*)(ws + 58720256);     // 16 MB  fragment-linear V
  u16* a_out   = (u16*)(ws + 75497472);     // 16 MB  (b,t,h*64+d)
  float* cost  = (float*)(ws + 92274688);   // 256 KB
  float* sint  = (float*)(ws + 92536832);   // 256 KB

  cvt_bf16<<<2048, 256, 0, stream>>>(x, x_bf, 8388608 / 4);
  cvt_bf16<<<768, 256, 0, stream>>>(Wqkv, wqkv_bf, 3145728 / 4);
  cvt_bf16<<<256, 256, 0, stream>>>(Wout, wout_bf, 1048576 / 4);
  rope_tab<<<256, 256, 0, stream>>>(cost, sint);
  gemm_qkv<<<dim3(24, 32), 512, 0, stream>>>(x_bf, wqkv_bf, qf_buf, kf_buf, vf_buf, cost, sint);
  attn_fwd<<<2048, 256, 0, stream>>>(qf_buf, kf_buf, vf_buf, a_out);
  gemm_out<<<dim3(16, 64), 256, 0, stream>>>(a_out, wout_bf, out);
}

// Round 13
// 186.200 us; speedup vs baseline: 4.8254x; 4.8254x over previous
//
#include <hip/hip_runtime.h>

typedef unsigned short u16;
typedef unsigned int   u32;
typedef __bf16 bf16;
typedef bf16  bf16x8 __attribute__((ext_vector_type(8)));
typedef u16   u16x8  __attribute__((ext_vector_type(8)));
typedef u32   u32x4  __attribute__((ext_vector_type(4)));
typedef float f32x4  __attribute__((ext_vector_type(4)));
typedef float f32x16 __attribute__((ext_vector_type(16)));

__device__ __forceinline__ u16 f2bf(float f) {
  u32 u = __builtin_bit_cast(u32, f);
  u32 r = u + 0x7fffu + ((u >> 16) & 1u);
  return (u16)(r >> 16);
}

__device__ __forceinline__ u32 cvtpk(float lo, float hi) {
  u32 r;
  asm("v_cvt_pk_bf16_f32 %0, %1, %2" : "=v"(r) : "v"(lo), "v"(hi));
  return r;
}

__device__ __forceinline__ bf16x8 ldb8(const u16* p) {
  return __builtin_bit_cast(bf16x8, *reinterpret_cast<const u16x8*>(p));
}

__device__ __forceinline__ f32x4 mfma16(bf16x8 a, bf16x8 b, f32x4 c) {
  return __builtin_amdgcn_mfma_f32_16x16x32_bf16(a, b, c, 0, 0, 0);
}

__device__ __forceinline__ f32x16 mfma32(bf16x8 a, bf16x8 b, f32x16 c) {
  return __builtin_amdgcn_mfma_f32_32x32x16_bf16(a, b, c, 0, 0, 0);
}

__device__ __forceinline__ void gl_lds16(const void* g, void* l) {
  __builtin_amdgcn_global_load_lds(
      (const __attribute__((address_space(1))) void*)g,
      (__attribute__((address_space(3))) void*)l, 16, 0, 0);
}

// unswizzled staging (gemm_out)
__device__ __forceinline__ void stage128x64(const u16* gbase, u16* lds, int tid) {
#pragma unroll
  for (int rd = 0; rd < 4; rd++) {
    int o = rd * 4096 + tid * 16;
    int row = o >> 7, colb = o & 127;
    gl_lds16((const char*)gbase + (size_t)row * 2048 + colb, (char*)lds + o);
  }
}
__device__ __forceinline__ void stage64x64(const u16* gbase, u16* lds, int tid) {
#pragma unroll
  for (int rd = 0; rd < 2; rd++) {
    int o = rd * 4096 + tid * 16;
    int row = o >> 7, colb = o & 127;
    gl_lds16((const char*)gbase + (size_t)row * 2048 + colb, (char*)lds + o);
  }
}

// swizzled staging for the 8-wave GEMM: LDS linear dest, pre-swizzled global src.
__device__ __forceinline__ void stage_swz(const u16* g, u16* lds, int tid, int rd) {
  int o = rd * 8192 + tid * 16;
  int row = o >> 7;
  int slot = (tid & 7) ^ (row & 7);
  gl_lds16((const char*)g + (size_t)row * 2048 + slot * 16, (char*)lds + o);
}

// Fragment-linear layouts (per bh: 131072 u16 = 256 KB):
__device__ __forceinline__ size_t qk_frag_addr(int bh, int t, int d) {
  return (size_t)bh * 131072 + (size_t)(t >> 5) * 2048 +
         (size_t)((d >> 4) * 512 + ((d >> 3) & 1) * 256 + (t & 31) * 8 + (d & 7));
}
__device__ __forceinline__ size_t v_frag_addr(int bh, int t, int d) {
  return (size_t)bh * 131072 + (size_t)(t >> 5) * 2048 +
         (size_t)((d >> 5) * 1024 + ((t >> 4) & 1) * 512 +
                  (((t >> 3) & 1) * 32 + (d & 31)) * 8 + (t & 7));
}

// ---------------- fp32 -> bf16 conversion ----------------
__global__ void cvt_bf16(const float* __restrict__ in, u16* __restrict__ out, int n4) {
  int stride = gridDim.x * blockDim.x;
  for (int i = blockIdx.x * blockDim.x + threadIdx.x; i < n4; i += stride) {
    float4 f = reinterpret_cast<const float4*>(in)[i];
    ushort4 o;
    o.x = f2bf(f.x); o.y = f2bf(f.y); o.z = f2bf(f.z); o.w = f2bf(f.w);
    reinterpret_cast<ushort4*>(out)[i] = o;
  }
}

// ---------------- RoPE tables: [2048][32] cos/sin ----------------
__global__ void rope_tab(float* __restrict__ ct, float* __restrict__ st) {
  int idx = blockIdx.x * 256 + threadIdx.x;
  int t = idx >> 5, i = idx & 31;
  float theta = exp2f(-(float)i * 0.4152410118609203f);
  float ang = (float)t * theta;
  ct[idx] = cosf(ang);
  st[idx] = sinf(ang);
}

// ---------------- QKV GEMM: 256x128 tile, 8 waves, 3-buffer counted-vmcnt -------
// T2 swizzle + T3 phases + T4 counted vmcnt(6) + T5 setprio.
__global__ __launch_bounds__(512) void gemm_qkv(
    const u16* __restrict__ xb, const u16* __restrict__ wb,
    u16* __restrict__ qfb, u16* __restrict__ kfb, u16* __restrict__ vfb,
    const float* __restrict__ cost, const float* __restrict__ sint) {
  __shared__ u16 As[3][256 * 64];   // 96 KB
  __shared__ u16 Bs[3][128 * 64];   // 48 KB
  int tid = threadIdx.x, lane = tid & 63, wid = tid >> 6;
  int wm = wid >> 1, wn = wid & 1;
  int lr = lane & 15, lk = lane >> 4;
  int m0 = blockIdx.y * 256, n0 = blockIdx.x * 128;
  const u16* gA = xb + (size_t)m0 * 1024;
  const u16* gB = wb + (size_t)n0 * 1024;
  int swz = lr & 7;

  f32x4 acc[4][4] = {};

  // prologue: stage tiles 0 and 1
#pragma unroll
  for (int rd = 0; rd < 4; rd++) stage_swz(gA, As[0], tid, rd);
#pragma unroll
  for (int rd = 0; rd < 2; rd++) stage_swz(gB, Bs[0], tid, rd);
#pragma unroll
  for (int rd = 0; rd < 4; rd++) stage_swz(gA + 64, As[1], tid, rd);
#pragma unroll
  for (int rd = 0; rd < 2; rd++) stage_swz(gB + 64, Bs[1], tid, rd);
  asm volatile("s_waitcnt vmcnt(6)" ::: "memory");   // tile 0 landed
  __builtin_amdgcn_s_barrier();

#pragma unroll 1
  for (int t = 0; t < 16; t++) {
    const u16* Ac = As[t % 3];
    const u16* Bc = Bs[t % 3];
    u16* An = As[(t + 2) % 3];
    u16* Bn = Bs[(t + 2) % 3];
    const u16* gAn = gA + (t + 2) * 64;
    const u16* gBn = gB + (t + 2) * 64;
    bool pf = (t <= 13);
    bf16x8 af[4], bfr[4];

    // ---- phase 0 (kk = 0) ----
#pragma unroll
    for (int mr = 0; mr < 4; mr++)
      af[mr] = ldb8(&Ac[(wm * 64 + mr * 16 + lr) * 64 + ((lk ^ swz) * 8)]);
#pragma unroll
    for (int nr = 0; nr < 4; nr++)
      bfr[nr] = ldb8(&Bc[(wn * 64 + nr * 16 + lr) * 64 + ((lk ^ swz) * 8)]);
    if (pf) {
      stage_swz(gAn, An, tid, 0);
      stage_swz(gAn, An, tid, 1);
      stage_swz(gBn, Bn, tid, 0);
    }
    __builtin_amdgcn_s_setprio(1);
#pragma unroll
    for (int mr = 0; mr < 4; mr++)
#pragma unroll
      for (int nr = 0; nr < 4; nr++)
        acc[mr][nr] = mfma16(af[mr], bfr[nr], acc[mr][nr]);
    __builtin_amdgcn_s_setprio(0);
    __builtin_amdgcn_s_barrier();

    // ---- phase 1 (kk = 1) ----
#pragma unroll
    for (int mr = 0; mr < 4; mr++)
      af[mr] = ldb8(&Ac[(wm * 64 + mr * 16 + lr) * 64 + (((lk + 4) ^ swz) * 8)]);
#pragma unroll
    for (int nr = 0; nr < 4; nr++)
      bfr[nr] = ldb8(&Bc[(wn * 64 + nr * 16 + lr) * 64 + (((lk + 4) ^ swz) * 8)]);
    if (pf) {
      stage_swz(gAn, An, tid, 2);
      stage_swz(gAn, An, tid, 3);
      stage_swz(gBn, Bn, tid, 1);
    }
    __builtin_amdgcn_s_setprio(1);
#pragma unroll
    for (int mr = 0; mr < 4; mr++)
#pragma unroll
      for (int nr = 0; nr < 4; nr++)
        acc[mr][nr] = mfma16(af[mr], bfr[nr], acc[mr][nr]);
    __builtin_amdgcn_s_setprio(0);
    // counted drain: tile t+1's loads must land before anyone's next ds_read.
    if (t < 14) {
      asm volatile("s_waitcnt vmcnt(6)" ::: "memory");
    } else if (t == 14) {
      asm volatile("s_waitcnt vmcnt(0)" ::: "memory");
    }
    __builtin_amdgcn_s_barrier();
  }

  const float CQ = 0.18033688011112042f;
  int sec = n0 >> 10;

  if (sec < 2) {
    u16* buf = (sec == 0) ? qfb : kfb;
    float scale = (sec == 0) ? CQ : 1.0f;
#pragma unroll
    for (int nr = 0; nr < 4; nr++) {
      int col = n0 + wn * 64 + nr * 16 + lr;
      int cc = col & 1023;
      int h = cc >> 6, d = cc & 63;
#pragma unroll
      for (int mr = 0; mr < 4; mr++) {
        int Mb = m0 + wm * 64 + mr * 16 + lk * 4;
#pragma unroll
        for (int r = 0; r < 4; r++) {
          int M = Mb + r;
          int b = M >> 11, tt = M & 2047;
          float val = acc[mr][nr][r];
          float par = __shfl_xor(val, 1);
          float c_ = cost[tt * 32 + (d >> 1)];
          float s_ = sint[tt * 32 + (d >> 1)];
          float res = (d & 1) ? (val * c_ + par * s_) : (val * c_ - par * s_);
          buf[qk_frag_addr(b * 16 + h, tt, d)] = f2bf(res * scale);
        }
      }
    }
  } else {
#pragma unroll
    for (int nr = 0; nr < 4; nr++) {
      int col = n0 + wn * 64 + nr * 16 + lr;
      int cc = col & 1023;
      int h = cc >> 6, d = cc & 63;
#pragma unroll
      for (int mr = 0; mr < 4; mr++) {
        int Mb = m0 + wm * 64 + mr * 16 + lk * 4;
        int b = Mb >> 11, tt = Mb & 2047;
        ushort4 pk;
        pk.x = f2bf(acc[mr][nr][0]); pk.y = f2bf(acc[mr][nr][1]);
        pk.z = f2bf(acc[mr][nr][2]); pk.w = f2bf(acc[mr][nr][3]);
        *reinterpret_cast<ushort4*>(&vfb[v_frag_addr(b * 16 + h, tt, d)]) = pk;
      }
    }
  }
}

// ---------------- Flash attention: 4-wave KV-split, shfl pack + MFMA row-sum -----
// NOTE: requires VGPR=64; __launch_bounds__(256,4) is load-bearing (2nd arg 8
// caps VGPR at 32 -> scratch spill -> 10x regression; measured R5, R12).
__device__ __forceinline__ void attn_step(
    const u16* __restrict__ kfb, const u16* __restrict__ vfb,
    const bf16x8* qf, bf16x8 ones, int kt, int qt, int qrow,
    int lane, int hi,
    f32x16& o0, f32x16& o1, f32x16& lsum, float& m_) {
  const u16* ktb = kfb + (size_t)kt * 2048;
  const u16* vtb = vfb + (size_t)kt * 2048;
  bf16x8 vf00 = ldb8(vtb + lane * 8);
  bf16x8 vf01 = ldb8(vtb + 512 + lane * 8);
  bf16x8 vf10 = ldb8(vtb + 1024 + lane * 8);
  bf16x8 vf11 = ldb8(vtb + 1536 + lane * 8);

  f32x16 sT = {};
#pragma unroll
  for (int s = 0; s < 4; s++) {
    bf16x8 kf = ldb8(ktb + s * 512 + lane * 8);
    sT = mfma32(kf, qf[s], sT);
  }
  if (kt == qt) {   // causal mask on diagonal tile
    int k0 = kt * 32;
#pragma unroll
    for (int r = 0; r < 16; r++) {
      int kvg = k0 + (r & 3) + 8 * (r >> 2) + 4 * hi;
      if (kvg > qrow) sT[r] = -3.0e38f;
    }
  }
  // row max: max3-fusable tree + 1 cross-half shfl
  float a0 = fmaxf(fmaxf(sT[0], sT[1]),  sT[2]);
  float a1 = fmaxf(fmaxf(sT[3], sT[4]),  sT[5]);
  float a2 = fmaxf(fmaxf(sT[6], sT[7]),  sT[8]);
  float a3 = fmaxf(fmaxf(sT[9], sT[10]), sT[11]);
  float a4 = fmaxf(fmaxf(sT[12], sT[13]), sT[14]);
  float b0 = fmaxf(fmaxf(a0, a1), a2);
  float b1 = fmaxf(fmaxf(a3, a4), sT[15]);
  float pm = fmaxf(b0, b1);
  pm = fmaxf(pm, __shfl_xor(pm, 32));

  if (__any(pm > m_ + 8.0f)) {    // defer-max
    float mn = fmaxf(m_, pm);
    float corr = exp2f(m_ - mn);
    lsum[0] *= corr;              // only [0] is ever read
    o0 *= corr; o1 *= corr;
    m_ = mn;
  }

  float p[16];
#pragma unroll
  for (int r = 0; r < 16; r++) p[r] = exp2f(sT[r] - m_);

  // pack P to bf16 pairs; exchange across lane halves (proven form)
  u32 c0 = cvtpk(p[0], p[1]),   c1 = cvtpk(p[2], p[3]);
  u32 c2 = cvtpk(p[4], p[5]),   c3 = cvtpk(p[6], p[7]);
  u32 c4 = cvtpk(p[8], p[9]),   c5 = cvtpk(p[10], p[11]);
  u32 c6 = cvtpk(p[12], p[13]), c7 = cvtpk(p[14], p[15]);
  u32 x0 = __shfl_xor((int)c0, 32), x1 = __shfl_xor((int)c1, 32);
  u32 x2 = __shfl_xor((int)c2, 32), x3 = __shfl_xor((int)c3, 32);
  u32 x4 = __shfl_xor((int)c4, 32), x5 = __shfl_xor((int)c5, 32);
  u32 x6 = __shfl_xor((int)c6, 32), x7 = __shfl_xor((int)c7, 32);
  u32x4 w0 = { hi ? x2 : c0, hi ? x3 : c1, hi ? c2 : x0, hi ? c3 : x1 };
  u32x4 w1 = { hi ? x6 : c4, hi ? x7 : c5, hi ? c6 : x4, hi ? c7 : x5 };
  bf16x8 pf0 = __builtin_bit_cast(bf16x8, w0);
  bf16x8 pf1 = __builtin_bit_cast(bf16x8, w1);

  // row-sum via MFMA (all-ones A)
  lsum = mfma32(ones, pf0, lsum);
  lsum = mfma32(ones, pf1, lsum);

  o0 = mfma32(vf00, pf0, o0);
  o0 = mfma32(vf01, pf1, o0);
  o1 = mfma32(vf10, pf0, o1);
  o1 = mfma32(vf11, pf1, o1);
}

__device__ __forceinline__ void stash_state(
    float* o_l, float* ml, int lane,
    const f32x16& o0, const f32x16& o1, float m_, float l_) {
#pragma unroll
  for (int r = 0; r < 16; r++) {
    o_l[r * 64 + lane]        = o0[r];
    o_l[(16 + r) * 64 + lane] = o1[r];
  }
  ml[lane]      = m_;
  ml[64 + lane] = l_;
}

__device__ __forceinline__ void merge_state(
    const float* o_l, const float* ml, int lane,
    f32x16& o0, f32x16& o1, float& m_, float& l_) {
  float me = ml[lane], le = ml[64 + lane];
  float mn = fmaxf(m_, me);
  float sc = exp2f(m_ - mn), se = exp2f(me - mn);
  l_ = l_ * sc + le * se;
#pragma unroll
  for (int r = 0; r < 16; r++) {
    o0[r] = o0[r] * sc + o_l[r * 64 + lane] * se;
    o1[r] = o1[r] * sc + o_l[(16 + r) * 64 + lane] * se;
  }
  m_ = mn;
}

__device__ __forceinline__ void attn_half(
    const u16* __restrict__ qfb, const u16* __restrict__ kfb,
    const u16* __restrict__ vfb, u16* __restrict__ og,
    float* o_lds, float* ml_lds, bf16x8 ones,
    int qt, int kt0, int w, int lane, int l31, int hi,
    size_t outbase) {
  int qrow = qt * 32 + l31;
  bf16x8 qf[4];
#pragma unroll
  for (int s = 0; s < 4; s++)
    qf[s] = ldb8(qfb + (size_t)qt * 2048 + s * 512 + lane * 8);

  f32x16 o0 = {}, o1 = {}, lsum = {};
  float m_ = -3.0e38f;

#pragma unroll 1
  for (int kt = kt0; kt <= qt; kt += 4)
    attn_step(kfb, vfb, qf, ones, kt, qt, qrow, lane, hi, o0, o1, lsum, m_);

  float l_ = lsum[0];

  if (w >= 2) stash_state(o_lds + (w - 2) * 2048, ml_lds + (w - 2) * 128, lane, o0, o1, m_, l_);
  __syncthreads();
  if (w < 2)  merge_state(o_lds + w * 2048, ml_lds + w * 128, lane, o0, o1, m_, l_);
  __syncthreads();
  if (w == 1) stash_state(o_lds, ml_lds, lane, o0, o1, m_, l_);
  __syncthreads();
  if (w == 0) {
    merge_state(o_lds, ml_lds, lane, o0, o1, m_, l_);
    float inv = 1.0f / l_;
    size_t base = outbase + (size_t)qrow * 1024;
#pragma unroll
    for (int db = 0; db < 2; db++) {
      f32x16 oo = db ? o1 : o0;
#pragma unroll
      for (int r = 0; r < 16; r += 2) {
        int d = db * 32 + (r & 3) + 8 * (r >> 2) + 4 * hi;
        u32 pk_ = cvtpk(oo[r] * inv, oo[r + 1] * inv);
        *reinterpret_cast<u32*>(&og[base + d]) = pk_;
      }
    }
  }
  __syncthreads();
}

__global__ __launch_bounds__(256, 4) void attn_fwd(
    const u16* __restrict__ qg, const u16* __restrict__ kg,
    const u16* __restrict__ vg, u16* __restrict__ og) {
  __shared__ float o_lds[2 * 32 * 64];
  __shared__ float ml_lds[2 * 2 * 64];
  int tid = threadIdx.x, lane = tid & 63, w = tid >> 6;
  int l31 = lane & 31, hi = lane >> 5;
  int blk = blockIdx.x;
  int bh = blk & 63, i = blk >> 6;
  const u16* qfb = qg + (size_t)bh * 131072;
  const u16* kfb = kg + (size_t)bh * 131072;
  const u16* vfb = vg + (size_t)bh * 131072;
  int hh = bh & 15, b = bh >> 4;
  size_t outbase = (size_t)b * 2048 * 1024 + hh * 64;

  u16x8 ov = {0x3F80, 0x3F80, 0x3F80, 0x3F80, 0x3F80, 0x3F80, 0x3F80, 0x3F80};
  bf16x8 ones = __builtin_bit_cast(bf16x8, ov);

  attn_half(qfb, kfb, vfb, og, o_lds, ml_lds, ones, i, w, w, lane, l31, hi, outbase);
  attn_half(qfb, kfb, vfb, og, o_lds, ml_lds, ones, 63 - i, (w - i - 1) & 3, w, lane, l31, hi, outbase);
}

// ---------------- Output GEMM (8192x1024x1024), 128x64 tiles, fp32 out ----------
__global__ __launch_bounds__(256) void gemm_out(
    const u16* __restrict__ ab, const u16* __restrict__ wb, float* __restrict__ out) {
  __shared__ u16 As[128 * 64];
  __shared__ u16 Bs[64 * 64];
  int tid = threadIdx.x, lane = tid & 63, w = tid >> 6;
  int wm = w >> 1, wn = w & 1;
  int lr = lane & 15, lk = lane >> 4;
  int m0 = blockIdx.y * 128, n0 = blockIdx.x * 64;

  f32x4 acc[4][2] = {};

  for (int k0 = 0; k0 < 1024; k0 += 64) {
    stage128x64(ab + (size_t)m0 * 1024 + k0, As, tid);
    stage64x64(wb + (size_t)n0 * 1024 + k0, Bs, tid);
    asm volatile("s_waitcnt vmcnt(0)" ::: "memory");
    __syncthreads();
#pragma unroll
    for (int kk = 0; kk < 2; kk++) {
      bf16x8 af[4], bfr[2];
#pragma unroll
      for (int mt = 0; mt < 4; mt++) af[mt]  = ldb8(&As[(64 * wm + 16 * mt + lr) * 64 + lk * 8 + 32 * kk]);
#pragma unroll
      for (int nt = 0; nt < 2; nt++) bfr[nt] = ldb8(&Bs[(32 * wn + 16 * nt + lr) * 64 + lk * 8 + 32 * kk]);
#pragma unroll
      for (int mt = 0; mt < 4; mt++)
#pragma unroll
        for (int nt = 0; nt < 2; nt++)
          acc[mt][nt] = mfma16(af[mt], bfr[nt], acc[mt][nt]);
    }
    __syncthreads();
  }

#pragma unroll
  for (int nt = 0; nt < 2; nt++) {
    int col = n0 + 32 * wn + 16 * nt + lr;
#pragma unroll
    for (int mt = 0; mt < 4; mt++) {
      int Mb = m0 + 64 * wm + 16 * mt + lk * 4;
#pragma unroll
      for (int r = 0; r < 4; r++) {
        out[(size_t)(Mb + r) * 1024 + col] = acc[mt][nt][r];
      }
    }
  }
}

// ---------------- launcher ----------------
extern "C" void kernel_launch(void* const* d_in, const int* in_sizes, int n_in,
                              void* d_out, int out_size, void* d_ws, size_t ws_size,
                              hipStream_t stream) {
  const float* x    = (const float*)d_in[0];
  const float* Wqkv = (const float*)d_in[2];
  const float* Wout = (const float*)d_in[3];
  float* out = (float*)d_out;
  char* ws = (char*)d_ws;

  u16* x_bf    = (u16*)(ws + 0);            // 16 MB
  u16* wqkv_bf = (u16*)(ws + 16777216);     // 6 MB
  u16* wout_bf = (u16*)(ws + 23068672);     // 2 MB
  u16* qf_buf  = (u16*)(ws + 25165824);     // 16 MB  fragment-linear Q (prescaled)
  u16* kf_buf  = (u16*)(ws + 41943040);     // 16 MB  fragment-linear K
  u16* vf_buf  = (u16*)(ws + 58720256);     // 16 MB  fragment-linear V
  u16* a_out   = (u16*)(ws + 75497472);     // 16 MB  (b,t,h*64+d)
  float* cost  = (float*)(ws + 92274688);   // 256 KB
  float* sint  = (float*)(ws + 92536832);   // 256 KB

  cvt_bf16<<<2048, 256, 0, stream>>>(x, x_bf, 8388608 / 4);
  cvt_bf16<<<768, 256, 0, stream>>>(Wqkv, wqkv_bf, 3145728 / 4);
  cvt_bf16<<<256, 256, 0, stream>>>(Wout, wout_bf, 1048576 / 4);
  rope_tab<<<256, 256, 0, stream>>>(cost, sint);
  gemm_qkv<<<dim3(24, 32), 512, 0, stream>>>(x_bf, wqkv_bf, qf_buf, kf_buf, vf_buf, cost, sint);
  attn_fwd<<<2048, 256, 0, stream>>>(qf_buf, kf_buf, vf_buf, a_out);
  gemm_out<<<dim3(16, 64), 256, 0, stream>>>(a_out, wout_bf, out);
}

// Round 14
// 179.383 us; speedup vs baseline: 5.0088x; 1.0380x over previous
//
#include <hip/hip_runtime.h>

typedef unsigned short u16;
typedef unsigned int   u32;
typedef __bf16 bf16;
typedef bf16  bf16x8 __attribute__((ext_vector_type(8)));
typedef u16   u16x8  __attribute__((ext_vector_type(8)));
typedef u32   u32x4  __attribute__((ext_vector_type(4)));
typedef float f32x4  __attribute__((ext_vector_type(4)));
typedef float f32x16 __attribute__((ext_vector_type(16)));

__device__ __forceinline__ u16 f2bf(float f) {
  u32 u = __builtin_bit_cast(u32, f);
  u32 r = u + 0x7fffu + ((u >> 16) & 1u);
  return (u16)(r >> 16);
}

__device__ __forceinline__ u32 cvtpk(float lo, float hi) {
  u32 r;
  asm("v_cvt_pk_bf16_f32 %0, %1, %2" : "=v"(r) : "v"(lo), "v"(hi));
  return r;
}

__device__ __forceinline__ bf16x8 ldb8(const u16* p) {
  return __builtin_bit_cast(bf16x8, *reinterpret_cast<const u16x8*>(p));
}

__device__ __forceinline__ f32x4 mfma16(bf16x8 a, bf16x8 b, f32x4 c) {
  return __builtin_amdgcn_mfma_f32_16x16x32_bf16(a, b, c, 0, 0, 0);
}

__device__ __forceinline__ f32x16 mfma32(bf16x8 a, bf16x8 b, f32x16 c) {
  return __builtin_amdgcn_mfma_f32_32x32x16_bf16(a, b, c, 0, 0, 0);
}

__device__ __forceinline__ void gl_lds16(const void* g, void* l) {
  __builtin_amdgcn_global_load_lds(
      (const __attribute__((address_space(1))) void*)g,
      (__attribute__((address_space(3))) void*)l, 16, 0, 0);
}

// swizzled staging for the 8-wave GEMMs: LDS linear dest, pre-swizzled global src.
// global row stride fixed at 2048 B (1024 u16 / 512 f32x... all our operands).
__device__ __forceinline__ void stage_swz(const u16* g, u16* lds, int tid, int rd) {
  int o = rd * 8192 + tid * 16;
  int row = o >> 7;
  int slot = (tid & 7) ^ (row & 7);
  gl_lds16((const char*)g + (size_t)row * 2048 + slot * 16, (char*)lds + o);
}

// Fragment-linear layouts (per bh: 131072 u16 = 256 KB):
__device__ __forceinline__ size_t qk_frag_addr(int bh, int t, int d) {
  return (size_t)bh * 131072 + (size_t)(t >> 5) * 2048 +
         (size_t)((d >> 4) * 512 + ((d >> 3) & 1) * 256 + (t & 31) * 8 + (d & 7));
}
__device__ __forceinline__ size_t v_frag_addr(int bh, int t, int d) {
  return (size_t)bh * 131072 + (size_t)(t >> 5) * 2048 +
         (size_t)((d >> 5) * 1024 + ((t >> 4) & 1) * 512 +
                  (((t >> 3) & 1) * 32 + (d & 31)) * 8 + (t & 7));
}

// ---------------- fp32 -> bf16 conversion ----------------
__global__ void cvt_bf16(const float* __restrict__ in, u16* __restrict__ out, int n4) {
  int stride = gridDim.x * blockDim.x;
  for (int i = blockIdx.x * blockDim.x + threadIdx.x; i < n4; i += stride) {
    float4 f = reinterpret_cast<const float4*>(in)[i];
    ushort4 o;
    o.x = f2bf(f.x); o.y = f2bf(f.y); o.z = f2bf(f.z); o.w = f2bf(f.w);
    reinterpret_cast<ushort4*>(out)[i] = o;
  }
}

// ---------------- RoPE tables: [2048][32] cos/sin ----------------
__global__ void rope_tab(float* __restrict__ ct, float* __restrict__ st) {
  int idx = blockIdx.x * 256 + threadIdx.x;
  int t = idx >> 5, i = idx & 31;
  float theta = exp2f(-(float)i * 0.4152410118609203f);
  float ang = (float)t * theta;
  ct[idx] = cosf(ang);
  st[idx] = sinf(ang);
}

// ---------------- QKV GEMM: 256x128 tile, 8 waves, 3-buffer counted-vmcnt -------
// T2 swizzle + T3 phases + T4 counted vmcnt(6) + T5 setprio.
__global__ __launch_bounds__(512) void gemm_qkv(
    const u16* __restrict__ xb, const u16* __restrict__ wb,
    u16* __restrict__ qfb, u16* __restrict__ kfb, u16* __restrict__ vfb,
    const float* __restrict__ cost, const float* __restrict__ sint) {
  __shared__ u16 As[3][256 * 64];   // 96 KB
  __shared__ u16 Bs[3][128 * 64];   // 48 KB
  int tid = threadIdx.x, lane = tid & 63, wid = tid >> 6;
  int wm = wid >> 1, wn = wid & 1;
  int lr = lane & 15, lk = lane >> 4;
  int m0 = blockIdx.y * 256, n0 = blockIdx.x * 128;
  const u16* gA = xb + (size_t)m0 * 1024;
  const u16* gB = wb + (size_t)n0 * 1024;
  int swz = lr & 7;

  f32x4 acc[4][4] = {};

  // prologue: stage tiles 0 and 1
#pragma unroll
  for (int rd = 0; rd < 4; rd++) stage_swz(gA, As[0], tid, rd);
#pragma unroll
  for (int rd = 0; rd < 2; rd++) stage_swz(gB, Bs[0], tid, rd);
#pragma unroll
  for (int rd = 0; rd < 4; rd++) stage_swz(gA + 64, As[1], tid, rd);
#pragma unroll
  for (int rd = 0; rd < 2; rd++) stage_swz(gB + 64, Bs[1], tid, rd);
  asm volatile("s_waitcnt vmcnt(6)" ::: "memory");   // tile 0 landed
  __builtin_amdgcn_s_barrier();

#pragma unroll 1
  for (int t = 0; t < 16; t++) {
    const u16* Ac = As[t % 3];
    const u16* Bc = Bs[t % 3];
    u16* An = As[(t + 2) % 3];
    u16* Bn = Bs[(t + 2) % 3];
    const u16* gAn = gA + (t + 2) * 64;
    const u16* gBn = gB + (t + 2) * 64;
    bool pf = (t <= 13);
    bf16x8 af[4], bfr[4];

    // ---- phase 0 (kk = 0) ----
#pragma unroll
    for (int mr = 0; mr < 4; mr++)
      af[mr] = ldb8(&Ac[(wm * 64 + mr * 16 + lr) * 64 + ((lk ^ swz) * 8)]);
#pragma unroll
    for (int nr = 0; nr < 4; nr++)
      bfr[nr] = ldb8(&Bc[(wn * 64 + nr * 16 + lr) * 64 + ((lk ^ swz) * 8)]);
    if (pf) {
      stage_swz(gAn, An, tid, 0);
      stage_swz(gAn, An, tid, 1);
      stage_swz(gBn, Bn, tid, 0);
    }
    __builtin_amdgcn_s_setprio(1);
#pragma unroll
    for (int mr = 0; mr < 4; mr++)
#pragma unroll
      for (int nr = 0; nr < 4; nr++)
        acc[mr][nr] = mfma16(af[mr], bfr[nr], acc[mr][nr]);
    __builtin_amdgcn_s_setprio(0);
    __builtin_amdgcn_s_barrier();

    // ---- phase 1 (kk = 1) ----
#pragma unroll
    for (int mr = 0; mr < 4; mr++)
      af[mr] = ldb8(&Ac[(wm * 64 + mr * 16 + lr) * 64 + (((lk + 4) ^ swz) * 8)]);
#pragma unroll
    for (int nr = 0; nr < 4; nr++)
      bfr[nr] = ldb8(&Bc[(wn * 64 + nr * 16 + lr) * 64 + (((lk + 4) ^ swz) * 8)]);
    if (pf) {
      stage_swz(gAn, An, tid, 2);
      stage_swz(gAn, An, tid, 3);
      stage_swz(gBn, Bn, tid, 1);
    }
    __builtin_amdgcn_s_setprio(1);
#pragma unroll
    for (int mr = 0; mr < 4; mr++)
#pragma unroll
      for (int nr = 0; nr < 4; nr++)
        acc[mr][nr] = mfma16(af[mr], bfr[nr], acc[mr][nr]);
    __builtin_amdgcn_s_setprio(0);
    // counted drain: tile t+1's loads must land before anyone's next ds_read.
    if (t < 14) {
      asm volatile("s_waitcnt vmcnt(6)" ::: "memory");
    } else if (t == 14) {
      asm volatile("s_waitcnt vmcnt(0)" ::: "memory");
    }
    __builtin_amdgcn_s_barrier();
  }

  const float CQ = 0.18033688011112042f;
  int sec = n0 >> 10;

  if (sec < 2) {
    u16* buf = (sec == 0) ? qfb : kfb;
    float scale = (sec == 0) ? CQ : 1.0f;
#pragma unroll
    for (int nr = 0; nr < 4; nr++) {
      int col = n0 + wn * 64 + nr * 16 + lr;
      int cc = col & 1023;
      int h = cc >> 6, d = cc & 63;
#pragma unroll
      for (int mr = 0; mr < 4; mr++) {
        int Mb = m0 + wm * 64 + mr * 16 + lk * 4;
#pragma unroll
        for (int r = 0; r < 4; r++) {
          int M = Mb + r;
          int b = M >> 11, tt = M & 2047;
          float val = acc[mr][nr][r];
          float par = __shfl_xor(val, 1);
          float c_ = cost[tt * 32 + (d >> 1)];
          float s_ = sint[tt * 32 + (d >> 1)];
          float res = (d & 1) ? (val * c_ + par * s_) : (val * c_ - par * s_);
          buf[qk_frag_addr(b * 16 + h, tt, d)] = f2bf(res * scale);
        }
      }
    }
  } else {
#pragma unroll
    for (int nr = 0; nr < 4; nr++) {
      int col = n0 + wn * 64 + nr * 16 + lr;
      int cc = col & 1023;
      int h = cc >> 6, d = cc & 63;
#pragma unroll
      for (int mr = 0; mr < 4; mr++) {
        int Mb = m0 + wm * 64 + mr * 16 + lk * 4;
        int b = Mb >> 11, tt = Mb & 2047;
        ushort4 pk;
        pk.x = f2bf(acc[mr][nr][0]); pk.y = f2bf(acc[mr][nr][1]);
        pk.z = f2bf(acc[mr][nr][2]); pk.w = f2bf(acc[mr][nr][3]);
        *reinterpret_cast<ushort4*>(&vfb[v_frag_addr(b * 16 + h, tt, d)]) = pk;
      }
    }
  }
}

// ---------------- Flash attention: 4-wave KV-split, shfl pack + MFMA row-sum -----
// NOTE: requires VGPR=64; __launch_bounds__(256,4) is load-bearing (2nd arg 8
// caps VGPR at 32 -> scratch spill -> 10x regression; measured R5, R12).
__device__ __forceinline__ void attn_step(
    const u16* __restrict__ kfb, const u16* __restrict__ vfb,
    const bf16x8* qf, bf16x8 ones, int kt, int qt, int qrow,
    int lane, int hi,
    f32x16& o0, f32x16& o1, f32x16& lsum, float& m_) {
  const u16* ktb = kfb + (size_t)kt * 2048;
  const u16* vtb = vfb + (size_t)kt * 2048;
  bf16x8 vf00 = ldb8(vtb + lane * 8);
  bf16x8 vf01 = ldb8(vtb + 512 + lane * 8);
  bf16x8 vf10 = ldb8(vtb + 1024 + lane * 8);
  bf16x8 vf11 = ldb8(vtb + 1536 + lane * 8);

  f32x16 sT = {};
#pragma unroll
  for (int s = 0; s < 4; s++) {
    bf16x8 kf = ldb8(ktb + s * 512 + lane * 8);
    sT = mfma32(kf, qf[s], sT);
  }
  if (kt == qt) {   // causal mask on diagonal tile
    int k0 = kt * 32;
#pragma unroll
    for (int r = 0; r < 16; r++) {
      int kvg = k0 + (r & 3) + 8 * (r >> 2) + 4 * hi;
      if (kvg > qrow) sT[r] = -3.0e38f;
    }
  }
  // row max: max3-fusable tree + 1 cross-half shfl
  float a0 = fmaxf(fmaxf(sT[0], sT[1]),  sT[2]);
  float a1 = fmaxf(fmaxf(sT[3], sT[4]),  sT[5]);
  float a2 = fmaxf(fmaxf(sT[6], sT[7]),  sT[8]);
  float a3 = fmaxf(fmaxf(sT[9], sT[10]), sT[11]);
  float a4 = fmaxf(fmaxf(sT[12], sT[13]), sT[14]);
  float b0 = fmaxf(fmaxf(a0, a1), a2);
  float b1 = fmaxf(fmaxf(a3, a4), sT[15]);
  float pm = fmaxf(b0, b1);
  pm = fmaxf(pm, __shfl_xor(pm, 32));

  if (__any(pm > m_ + 8.0f)) {    // defer-max
    float mn = fmaxf(m_, pm);
    float corr = exp2f(m_ - mn);
    lsum[0] *= corr;              // only [0] is ever read
    o0 *= corr; o1 *= corr;
    m_ = mn;
  }

  float p[16];
#pragma unroll
  for (int r = 0; r < 16; r++) p[r] = exp2f(sT[r] - m_);

  // pack P to bf16 pairs; exchange across lane halves (proven form)
  u32 c0 = cvtpk(p[0], p[1]),   c1 = cvtpk(p[2], p[3]);
  u32 c2 = cvtpk(p[4], p[5]),   c3 = cvtpk(p[6], p[7]);
  u32 c4 = cvtpk(p[8], p[9]),   c5 = cvtpk(p[10], p[11]);
  u32 c6 = cvtpk(p[12], p[13]), c7 = cvtpk(p[14], p[15]);
  u32 x0 = __shfl_xor((int)c0, 32), x1 = __shfl_xor((int)c1, 32);
  u32 x2 = __shfl_xor((int)c2, 32), x3 = __shfl_xor((int)c3, 32);
  u32 x4 = __shfl_xor((int)c4, 32), x5 = __shfl_xor((int)c5, 32);
  u32 x6 = __shfl_xor((int)c6, 32), x7 = __shfl_xor((int)c7, 32);
  u32x4 w0 = { hi ? x2 : c0, hi ? x3 : c1, hi ? c2 : x0, hi ? c3 : x1 };
  u32x4 w1 = { hi ? x6 : c4, hi ? x7 : c5, hi ? c6 : x4, hi ? c7 : x5 };
  bf16x8 pf0 = __builtin_bit_cast(bf16x8, w0);
  bf16x8 pf1 = __builtin_bit_cast(bf16x8, w1);

  // row-sum via MFMA (all-ones A)
  lsum = mfma32(ones, pf0, lsum);
  lsum = mfma32(ones, pf1, lsum);

  o0 = mfma32(vf00, pf0, o0);
  o0 = mfma32(vf01, pf1, o0);
  o1 = mfma32(vf10, pf0, o1);
  o1 = mfma32(vf11, pf1, o1);
}

__device__ __forceinline__ void stash_state(
    float* o_l, float* ml, int lane,
    const f32x16& o0, const f32x16& o1, float m_, float l_) {
#pragma unroll
  for (int r = 0; r < 16; r++) {
    o_l[r * 64 + lane]        = o0[r];
    o_l[(16 + r) * 64 + lane] = o1[r];
  }
  ml[lane]      = m_;
  ml[64 + lane] = l_;
}

__device__ __forceinline__ void merge_state(
    const float* o_l, const float* ml, int lane,
    f32x16& o0, f32x16& o1, float& m_, float& l_) {
  float me = ml[lane], le = ml[64 + lane];
  float mn = fmaxf(m_, me);
  float sc = exp2f(m_ - mn), se = exp2f(me - mn);
  l_ = l_ * sc + le * se;
#pragma unroll
  for (int r = 0; r < 16; r++) {
    o0[r] = o0[r] * sc + o_l[r * 64 + lane] * se;
    o1[r] = o1[r] * sc + o_l[(16 + r) * 64 + lane] * se;
  }
  m_ = mn;
}

__device__ __forceinline__ void attn_half(
    const u16* __restrict__ qfb, const u16* __restrict__ kfb,
    const u16* __restrict__ vfb, u16* __restrict__ og,
    float* o_lds, float* ml_lds, bf16x8 ones,
    int qt, int kt0, int w, int lane, int l31, int hi,
    size_t outbase) {
  int qrow = qt * 32 + l31;
  bf16x8 qf[4];
#pragma unroll
  for (int s = 0; s < 4; s++)
    qf[s] = ldb8(qfb + (size_t)qt * 2048 + s * 512 + lane * 8);

  f32x16 o0 = {}, o1 = {}, lsum = {};
  float m_ = -3.0e38f;

#pragma unroll 1
  for (int kt = kt0; kt <= qt; kt += 4)
    attn_step(kfb, vfb, qf, ones, kt, qt, qrow, lane, hi, o0, o1, lsum, m_);

  float l_ = lsum[0];

  if (w >= 2) stash_state(o_lds + (w - 2) * 2048, ml_lds + (w - 2) * 128, lane, o0, o1, m_, l_);
  __syncthreads();
  if (w < 2)  merge_state(o_lds + w * 2048, ml_lds + w * 128, lane, o0, o1, m_, l_);
  __syncthreads();
  if (w == 1) stash_state(o_lds, ml_lds, lane, o0, o1, m_, l_);
  __syncthreads();
  if (w == 0) {
    merge_state(o_lds, ml_lds, lane, o0, o1, m_, l_);
    float inv = 1.0f / l_;
    size_t base = outbase + (size_t)qrow * 1024;
#pragma unroll
    for (int db = 0; db < 2; db++) {
      f32x16 oo = db ? o1 : o0;
#pragma unroll
      for (int r = 0; r < 16; r += 2) {
        int d = db * 32 + (r & 3) + 8 * (r >> 2) + 4 * hi;
        u32 pk_ = cvtpk(oo[r] * inv, oo[r + 1] * inv);
        *reinterpret_cast<u32*>(&og[base + d]) = pk_;
      }
    }
  }
  __syncthreads();
}

__global__ __launch_bounds__(256, 4) void attn_fwd(
    const u16* __restrict__ qg, const u16* __restrict__ kg,
    const u16* __restrict__ vg, u16* __restrict__ og) {
  __shared__ float o_lds[2 * 32 * 64];
  __shared__ float ml_lds[2 * 2 * 64];
  int tid = threadIdx.x, lane = tid & 63, w = tid >> 6;
  int l31 = lane & 31, hi = lane >> 5;
  int blk = blockIdx.x;
  int bh = blk & 63, i = blk >> 6;
  const u16* qfb = qg + (size_t)bh * 131072;
  const u16* kfb = kg + (size_t)bh * 131072;
  const u16* vfb = vg + (size_t)bh * 131072;
  int hh = bh & 15, b = bh >> 4;
  size_t outbase = (size_t)b * 2048 * 1024 + hh * 64;

  u16x8 ov = {0x3F80, 0x3F80, 0x3F80, 0x3F80, 0x3F80, 0x3F80, 0x3F80, 0x3F80};
  bf16x8 ones = __builtin_bit_cast(bf16x8, ov);

  attn_half(qfb, kfb, vfb, og, o_lds, ml_lds, ones, i, w, w, lane, l31, hi, outbase);
  attn_half(qfb, kfb, vfb, og, o_lds, ml_lds, ones, 63 - i, (w - i - 1) & 3, w, lane, l31, hi, outbase);
}

// ---------------- Output GEMM: 256x128 tile, 8 waves, 3-buffer counted-vmcnt ----
// Same template as gemm_qkv; fp32 epilogue. Grid (8,32) = 256 blocks = 1/CU.
__global__ __launch_bounds__(512) void gemm_out(
    const u16* __restrict__ ab, const u16* __restrict__ wb, float* __restrict__ out) {
  __shared__ u16 As[3][256 * 64];   // 96 KB
  __shared__ u16 Bs[3][128 * 64];   // 48 KB
  int tid = threadIdx.x, lane = tid & 63, wid = tid >> 6;
  int wm = wid >> 1, wn = wid & 1;
  int lr = lane & 15, lk = lane >> 4;
  int m0 = blockIdx.y * 256, n0 = blockIdx.x * 128;
  const u16* gA = ab + (size_t)m0 * 1024;
  const u16* gB = wb + (size_t)n0 * 1024;
  int swz = lr & 7;

  f32x4 acc[4][4] = {};

#pragma unroll
  for (int rd = 0; rd < 4; rd++) stage_swz(gA, As[0], tid, rd);
#pragma unroll
  for (int rd = 0; rd < 2; rd++) stage_swz(gB, Bs[0], tid, rd);
#pragma unroll
  for (int rd = 0; rd < 4; rd++) stage_swz(gA + 64, As[1], tid, rd);
#pragma unroll
  for (int rd = 0; rd < 2; rd++) stage_swz(gB + 64, Bs[1], tid, rd);
  asm volatile("s_waitcnt vmcnt(6)" ::: "memory");
  __builtin_amdgcn_s_barrier();

#pragma unroll 1
  for (int t = 0; t < 16; t++) {
    const u16* Ac = As[t % 3];
    const u16* Bc = Bs[t % 3];
    u16* An = As[(t + 2) % 3];
    u16* Bn = Bs[(t + 2) % 3];
    const u16* gAn = gA + (t + 2) * 64;
    const u16* gBn = gB + (t + 2) * 64;
    bool pf = (t <= 13);
    bf16x8 af[4], bfr[4];

    // ---- phase 0 ----
#pragma unroll
    for (int mr = 0; mr < 4; mr++)
      af[mr] = ldb8(&Ac[(wm * 64 + mr * 16 + lr) * 64 + ((lk ^ swz) * 8)]);
#pragma unroll
    for (int nr = 0; nr < 4; nr++)
      bfr[nr] = ldb8(&Bc[(wn * 64 + nr * 16 + lr) * 64 + ((lk ^ swz) * 8)]);
    if (pf) {
      stage_swz(gAn, An, tid, 0);
      stage_swz(gAn, An, tid, 1);
      stage_swz(gBn, Bn, tid, 0);
    }
    __builtin_amdgcn_s_setprio(1);
#pragma unroll
    for (int mr = 0; mr < 4; mr++)
#pragma unroll
      for (int nr = 0; nr < 4; nr++)
        acc[mr][nr] = mfma16(af[mr], bfr[nr], acc[mr][nr]);
    __builtin_amdgcn_s_setprio(0);
    __builtin_amdgcn_s_barrier();

    // ---- phase 1 ----
#pragma unroll
    for (int mr = 0; mr < 4; mr++)
      af[mr] = ldb8(&Ac[(wm * 64 + mr * 16 + lr) * 64 + (((lk + 4) ^ swz) * 8)]);
#pragma unroll
    for (int nr = 0; nr < 4; nr++)
      bfr[nr] = ldb8(&Bc[(wn * 64 + nr * 16 + lr) * 64 + (((lk + 4) ^ swz) * 8)]);
    if (pf) {
      stage_swz(gAn, An, tid, 2);
      stage_swz(gAn, An, tid, 3);
      stage_swz(gBn, Bn, tid, 1);
    }
    __builtin_amdgcn_s_setprio(1);
#pragma unroll
    for (int mr = 0; mr < 4; mr++)
#pragma unroll
      for (int nr = 0; nr < 4; nr++)
        acc[mr][nr] = mfma16(af[mr], bfr[nr], acc[mr][nr]);
    __builtin_amdgcn_s_setprio(0);
    if (t < 14) {
      asm volatile("s_waitcnt vmcnt(6)" ::: "memory");
    } else if (t == 14) {
      asm volatile("s_waitcnt vmcnt(0)" ::: "memory");
    }
    __builtin_amdgcn_s_barrier();
  }

  // fp32 epilogue: coalesced dword stores
#pragma unroll
  for (int nr = 0; nr < 4; nr++) {
    int col = n0 + wn * 64 + nr * 16 + lr;
#pragma unroll
    for (int mr = 0; mr < 4; mr++) {
      int Mb = m0 + wm * 64 + mr * 16 + lk * 4;
#pragma unroll
      for (int r = 0; r < 4; r++) {
        out[(size_t)(Mb + r) * 1024 + col] = acc[mr][nr][r];
      }
    }
  }
}

// ---------------- launcher ----------------
extern "C" void kernel_launch(void* const* d_in, const int* in_sizes, int n_in,
                              void* d_out, int out_size, void* d_ws, size_t ws_size,
                              hipStream_t stream) {
  const float* x    = (const float*)d_in[0];
  const float* Wqkv = (const float*)d_in[2];
  const float* Wout = (const float*)d_in[3];
  float* out = (float*)d_out;
  char* ws = (char*)d_ws;

  u16* x_bf    = (u16*)(ws + 0);            // 16 MB
  u16* wqkv_bf = (u16*)(ws + 16777216);     // 6 MB
  u16* wout_bf = (u16*)(ws + 23068672);     // 2 MB
  u16* qf_buf  = (u16*)(ws + 25165824);     // 16 MB  fragment-linear Q (prescaled)
  u16* kf_buf  = (u16*)(ws + 41943040);     // 16 MB  fragment-linear K
  u16* vf_buf  = (u16*)(ws + 58720256);     // 16 MB  fragment-linear V
  u16* a_out   = (u16*)(ws + 75497472);     // 16 MB  (b,t,h*64+d)
  float* cost  = (float*)(ws + 92274688);   // 256 KB
  float* sint  = (float*)(ws + 92536832);   // 256 KB

  cvt_bf16<<<2048, 256, 0, stream>>>(x, x_bf, 8388608 / 4);
  cvt_bf16<<<768, 256, 0, stream>>>(Wqkv, wqkv_bf, 3145728 / 4);
  cvt_bf16<<<256, 256, 0, stream>>>(Wout, wout_bf, 1048576 / 4);
  rope_tab<<<256, 256, 0, stream>>>(cost, sint);
  gemm_qkv<<<dim3(24, 32), 512, 0, stream>>>(x_bf, wqkv_bf, qf_buf, kf_buf, vf_buf, cost, sint);
  attn_fwd<<<2048, 256, 0, stream>>>(qf_buf, kf_buf, vf_buf, a_out);
  gemm_out<<<dim3(8, 32), 512, 0, stream>>>(a_out, wout_bf, out);
}

// Round 15
// 171.360 us; speedup vs baseline: 5.2433x; 1.0468x over previous
//
#include <hip/hip_runtime.h>

typedef unsigned short u16;
typedef unsigned int   u32;
typedef __bf16 bf16;
typedef bf16  bf16x8 __attribute__((ext_vector_type(8)));
typedef u16   u16x8  __attribute__((ext_vector_type(8)));
typedef u32   u32x4  __attribute__((ext_vector_type(4)));
typedef float f32x4  __attribute__((ext_vector_type(4)));
typedef float f32x16 __attribute__((ext_vector_type(16)));

__device__ __forceinline__ u16 f2bf(float f) {
  u32 u = __builtin_bit_cast(u32, f);
  u32 r = u + 0x7fffu + ((u >> 16) & 1u);
  return (u16)(r >> 16);
}

__device__ __forceinline__ u32 cvtpk(float lo, float hi) {
  u32 r;
  asm("v_cvt_pk_bf16_f32 %0, %1, %2" : "=v"(r) : "v"(lo), "v"(hi));
  return r;
}

__device__ __forceinline__ bf16x8 ldb8(const u16* p) {
  return __builtin_bit_cast(bf16x8, *reinterpret_cast<const u16x8*>(p));
}

__device__ __forceinline__ f32x4 mfma16(bf16x8 a, bf16x8 b, f32x4 c) {
  return __builtin_amdgcn_mfma_f32_16x16x32_bf16(a, b, c, 0, 0, 0);
}

__device__ __forceinline__ f32x16 mfma32(bf16x8 a, bf16x8 b, f32x16 c) {
  return __builtin_amdgcn_mfma_f32_32x32x16_bf16(a, b, c, 0, 0, 0);
}

__device__ __forceinline__ void gl_lds16(const void* g, void* l) {
  __builtin_amdgcn_global_load_lds(
      (const __attribute__((address_space(1))) void*)g,
      (__attribute__((address_space(3))) void*)l, 16, 0, 0);
}

// swizzled staging for the 8-wave GEMMs: LDS linear dest, pre-swizzled global src.
// global row stride fixed at 2048 B.
__device__ __forceinline__ void stage_swz(const u16* g, u16* lds, int tid, int rd) {
  int o = rd * 8192 + tid * 16;
  int row = o >> 7;
  int slot = (tid & 7) ^ (row & 7);
  gl_lds16((const char*)g + (size_t)row * 2048 + slot * 16, (char*)lds + o);
}

// Fragment-linear layouts (per bh: 131072 u16 = 256 KB):
__device__ __forceinline__ size_t qk_frag_addr(int bh, int t, int d) {
  return (size_t)bh * 131072 + (size_t)(t >> 5) * 2048 +
         (size_t)((d >> 4) * 512 + ((d >> 3) & 1) * 256 + (t & 31) * 8 + (d & 7));
}
__device__ __forceinline__ size_t v_frag_addr(int bh, int t, int d) {
  return (size_t)bh * 131072 + (size_t)(t >> 5) * 2048 +
         (size_t)((d >> 5) * 1024 + ((t >> 4) & 1) * 512 +
                  (((t >> 3) & 1) * 32 + (d & 31)) * 8 + (t & 7));
}

// ---------------- fused prep: fp32->bf16 (x, Wqkv, Wout) + RoPE tables ----------
// float4 ranges: x 2097152, Wqkv 786432, Wout 262144 (total 3145728)
__global__ void prep(const float* __restrict__ x, const float* __restrict__ wqkv,
                     const float* __restrict__ wout,
                     u16* __restrict__ xb, u16* __restrict__ wqb, u16* __restrict__ wob,
                     float* __restrict__ ct, float* __restrict__ st) {
  int i0 = blockIdx.x * 256 + threadIdx.x;
  int stride = gridDim.x * 256;
  for (int j = i0; j < 3145728; j += stride) {
    const float* src;
    u16* dst;
    int off;
    if (j < 2097152)      { src = x;    dst = xb;  off = j; }
    else if (j < 2883584) { src = wqkv; dst = wqb; off = j - 2097152; }
    else                  { src = wout; dst = wob; off = j - 2883584; }
    float4 f = reinterpret_cast<const float4*>(src)[off];
    ushort4 o;
    o.x = f2bf(f.x); o.y = f2bf(f.y); o.z = f2bf(f.z); o.w = f2bf(f.w);
    reinterpret_cast<ushort4*>(dst)[off] = o;
  }
  if (i0 < 65536) {   // rope tables [2048][32]
    int t = i0 >> 5, i = i0 & 31;
    float theta = exp2f(-(float)i * 0.4152410118609203f);
    float ang = (float)t * theta;
    ct[i0] = cosf(ang);
    st[i0] = sinf(ang);
  }
}

// ---------------- QKV GEMM: 256x128 tile, 8 waves, 3-buffer counted-vmcnt -------
// T1 XCD swizzle + T2 swizzle + T3 phases + T4 counted vmcnt(6) + T5 setprio.
__global__ __launch_bounds__(512) void gemm_qkv(
    const u16* __restrict__ xb, const u16* __restrict__ wb,
    u16* __restrict__ qfb, u16* __restrict__ kfb, u16* __restrict__ vfb,
    const float* __restrict__ cost, const float* __restrict__ sint) {
  __shared__ u16 As[3][256 * 64];   // 96 KB
  __shared__ u16 Bs[3][128 * 64];   // 48 KB
  int tid = threadIdx.x, lane = tid & 63, wid = tid >> 6;
  int wm = wid >> 1, wn = wid & 1;
  int lr = lane & 15, lk = lane >> 4;
  // T1: bijective XCD remap (grid 24x32=768, 768%8==0). Same-A-panel blocks
  // (same y) land on one XCD -> A-panel fetched once, not 8x.
  int orig = blockIdx.x + blockIdx.y * 24;
  int swzb = (orig & 7) * 96 + (orig >> 3);
  int m0 = (swzb / 24) * 256, n0 = (swzb % 24) * 128;
  const u16* gA = xb + (size_t)m0 * 1024;
  const u16* gB = wb + (size_t)n0 * 1024;
  int swz = lr & 7;

  f32x4 acc[4][4] = {};

  // prologue: stage tiles 0 and 1
#pragma unroll
  for (int rd = 0; rd < 4; rd++) stage_swz(gA, As[0], tid, rd);
#pragma unroll
  for (int rd = 0; rd < 2; rd++) stage_swz(gB, Bs[0], tid, rd);
#pragma unroll
  for (int rd = 0; rd < 4; rd++) stage_swz(gA + 64, As[1], tid, rd);
#pragma unroll
  for (int rd = 0; rd < 2; rd++) stage_swz(gB + 64, Bs[1], tid, rd);
  asm volatile("s_waitcnt vmcnt(6)" ::: "memory");   // tile 0 landed
  __builtin_amdgcn_s_barrier();

#pragma unroll 1
  for (int t = 0; t < 16; t++) {
    const u16* Ac = As[t % 3];
    const u16* Bc = Bs[t % 3];
    u16* An = As[(t + 2) % 3];
    u16* Bn = Bs[(t + 2) % 3];
    const u16* gAn = gA + (t + 2) * 64;
    const u16* gBn = gB + (t + 2) * 64;
    bool pf = (t <= 13);
    bf16x8 af[4], bfr[4];

    // ---- phase 0 (kk = 0) ----
#pragma unroll
    for (int mr = 0; mr < 4; mr++)
      af[mr] = ldb8(&Ac[(wm * 64 + mr * 16 + lr) * 64 + ((lk ^ swz) * 8)]);
#pragma unroll
    for (int nr = 0; nr < 4; nr++)
      bfr[nr] = ldb8(&Bc[(wn * 64 + nr * 16 + lr) * 64 + ((lk ^ swz) * 8)]);
    if (pf) {
      stage_swz(gAn, An, tid, 0);
      stage_swz(gAn, An, tid, 1);
      stage_swz(gBn, Bn, tid, 0);
    }
    __builtin_amdgcn_s_setprio(1);
#pragma unroll
    for (int mr = 0; mr < 4; mr++)
#pragma unroll
      for (int nr = 0; nr < 4; nr++)
        acc[mr][nr] = mfma16(af[mr], bfr[nr], acc[mr][nr]);
    __builtin_amdgcn_s_setprio(0);
    __builtin_amdgcn_s_barrier();

    // ---- phase 1 (kk = 1) ----
#pragma unroll
    for (int mr = 0; mr < 4; mr++)
      af[mr] = ldb8(&Ac[(wm * 64 + mr * 16 + lr) * 64 + (((lk + 4) ^ swz) * 8)]);
#pragma unroll
    for (int nr = 0; nr < 4; nr++)
      bfr[nr] = ldb8(&Bc[(wn * 64 + nr * 16 + lr) * 64 + (((lk + 4) ^ swz) * 8)]);
    if (pf) {
      stage_swz(gAn, An, tid, 2);
      stage_swz(gAn, An, tid, 3);
      stage_swz(gBn, Bn, tid, 1);
    }
    __builtin_amdgcn_s_setprio(1);
#pragma unroll
    for (int mr = 0; mr < 4; mr++)
#pragma unroll
      for (int nr = 0; nr < 4; nr++)
        acc[mr][nr] = mfma16(af[mr], bfr[nr], acc[mr][nr]);
    __builtin_amdgcn_s_setprio(0);
    // counted drain: tile t+1's loads must land before anyone's next ds_read.
    if (t < 14) {
      asm volatile("s_waitcnt vmcnt(6)" ::: "memory");
    } else if (t == 14) {
      asm volatile("s_waitcnt vmcnt(0)" ::: "memory");
    }
    __builtin_amdgcn_s_barrier();
  }

  const float CQ = 0.18033688011112042f;
  int sec = n0 >> 10;

  if (sec < 2) {
    u16* buf = (sec == 0) ? qfb : kfb;
    float scale = (sec == 0) ? CQ : 1.0f;
#pragma unroll
    for (int nr = 0; nr < 4; nr++) {
      int col = n0 + wn * 64 + nr * 16 + lr;
      int cc = col & 1023;
      int h = cc >> 6, d = cc & 63;
#pragma unroll
      for (int mr = 0; mr < 4; mr++) {
        int Mb = m0 + wm * 64 + mr * 16 + lk * 4;
#pragma unroll
        for (int r = 0; r < 4; r++) {
          int M = Mb + r;
          int b = M >> 11, tt = M & 2047;
          float val = acc[mr][nr][r];
          float par = __shfl_xor(val, 1);
          float c_ = cost[tt * 32 + (d >> 1)];
          float s_ = sint[tt * 32 + (d >> 1)];
          float res = (d & 1) ? (val * c_ + par * s_) : (val * c_ - par * s_);
          buf[qk_frag_addr(b * 16 + h, tt, d)] = f2bf(res * scale);
        }
      }
    }
  } else {
#pragma unroll
    for (int nr = 0; nr < 4; nr++) {
      int col = n0 + wn * 64 + nr * 16 + lr;
      int cc = col & 1023;
      int h = cc >> 6, d = cc & 63;
#pragma unroll
      for (int mr = 0; mr < 4; mr++) {
        int Mb = m0 + wm * 64 + mr * 16 + lk * 4;
        int b = Mb >> 11, tt = Mb & 2047;
        ushort4 pk;
        pk.x = f2bf(acc[mr][nr][0]); pk.y = f2bf(acc[mr][nr][1]);
        pk.z = f2bf(acc[mr][nr][2]); pk.w = f2bf(acc[mr][nr][3]);
        *reinterpret_cast<ushort4*>(&vfb[v_frag_addr(b * 16 + h, tt, d)]) = pk;
      }
    }
  }
}

// ---------------- Flash attention: 4-wave KV-split, shfl pack + MFMA row-sum -----
// NOTE: requires VGPR=64; __launch_bounds__(256,4) is load-bearing (2nd arg 8
// caps VGPR at 32 -> scratch spill -> 10x regression; measured R5, R12).
__device__ __forceinline__ void attn_step(
    const u16* __restrict__ kfb, const u16* __restrict__ vfb,
    const bf16x8* qf, bf16x8 ones, int kt, int qt, int qrow,
    int lane, int hi,
    f32x16& o0, f32x16& o1, f32x16& lsum, float& m_) {
  const u16* ktb = kfb + (size_t)kt * 2048;
  const u16* vtb = vfb + (size_t)kt * 2048;
  bf16x8 vf00 = ldb8(vtb + lane * 8);
  bf16x8 vf01 = ldb8(vtb + 512 + lane * 8);
  bf16x8 vf10 = ldb8(vtb + 1024 + lane * 8);
  bf16x8 vf11 = ldb8(vtb + 1536 + lane * 8);

  f32x16 sT = {};
#pragma unroll
  for (int s = 0; s < 4; s++) {
    bf16x8 kf = ldb8(ktb + s * 512 + lane * 8);
    sT = mfma32(kf, qf[s], sT);
  }
  if (kt == qt) {   // causal mask on diagonal tile
    int k0 = kt * 32;
#pragma unroll
    for (int r = 0; r < 16; r++) {
      int kvg = k0 + (r & 3) + 8 * (r >> 2) + 4 * hi;
      if (kvg > qrow) sT[r] = -3.0e38f;
    }
  }
  // row max: max3-fusable tree + 1 cross-half shfl
  float a0 = fmaxf(fmaxf(sT[0], sT[1]),  sT[2]);
  float a1 = fmaxf(fmaxf(sT[3], sT[4]),  sT[5]);
  float a2 = fmaxf(fmaxf(sT[6], sT[7]),  sT[8]);
  float a3 = fmaxf(fmaxf(sT[9], sT[10]), sT[11]);
  float a4 = fmaxf(fmaxf(sT[12], sT[13]), sT[14]);
  float b0 = fmaxf(fmaxf(a0, a1), a2);
  float b1 = fmaxf(fmaxf(a3, a4), sT[15]);
  float pm = fmaxf(b0, b1);
  pm = fmaxf(pm, __shfl_xor(pm, 32));

  if (__any(pm > m_ + 8.0f)) {    // defer-max
    float mn = fmaxf(m_, pm);
    float corr = exp2f(m_ - mn);
    lsum[0] *= corr;              // only [0] is ever read
    o0 *= corr; o1 *= corr;
    m_ = mn;
  }

  float p[16];
#pragma unroll
  for (int r = 0; r < 16; r++) p[r] = exp2f(sT[r] - m_);

  // pack P to bf16 pairs; exchange across lane halves (proven form)
  u32 c0 = cvtpk(p[0], p[1]),   c1 = cvtpk(p[2], p[3]);
  u32 c2 = cvtpk(p[4], p[5]),   c3 = cvtpk(p[6], p[7]);
  u32 c4 = cvtpk(p[8], p[9]),   c5 = cvtpk(p[10], p[11]);
  u32 c6 = cvtpk(p[12], p[13]), c7 = cvtpk(p[14], p[15]);
  u32 x0 = __shfl_xor((int)c0, 32), x1 = __shfl_xor((int)c1, 32);
  u32 x2 = __shfl_xor((int)c2, 32), x3 = __shfl_xor((int)c3, 32);
  u32 x4 = __shfl_xor((int)c4, 32), x5 = __shfl_xor((int)c5, 32);
  u32 x6 = __shfl_xor((int)c6, 32), x7 = __shfl_xor((int)c7, 32);
  u32x4 w0 = { hi ? x2 : c0, hi ? x3 : c1, hi ? c2 : x0, hi ? c3 : x1 };
  u32x4 w1 = { hi ? x6 : c4, hi ? x7 : c5, hi ? c6 : x4, hi ? c7 : x5 };
  bf16x8 pf0 = __builtin_bit_cast(bf16x8, w0);
  bf16x8 pf1 = __builtin_bit_cast(bf16x8, w1);

  // row-sum via MFMA (all-ones A)
  lsum = mfma32(ones, pf0, lsum);
  lsum = mfma32(ones, pf1, lsum);

  o0 = mfma32(vf00, pf0, o0);
  o0 = mfma32(vf01, pf1, o0);
  o1 = mfma32(vf10, pf0, o1);
  o1 = mfma32(vf11, pf1, o1);
}

__device__ __forceinline__ void stash_state(
    float* o_l, float* ml, int lane,
    const f32x16& o0, const f32x16& o1, float m_, float l_) {
#pragma unroll
  for (int r = 0; r < 16; r++) {
    o_l[r * 64 + lane]        = o0[r];
    o_l[(16 + r) * 64 + lane] = o1[r];
  }
  ml[lane]      = m_;
  ml[64 + lane] = l_;
}

__device__ __forceinline__ void merge_state(
    const float* o_l, const float* ml, int lane,
    f32x16& o0, f32x16& o1, float& m_, float& l_) {
  float me = ml[lane], le = ml[64 + lane];
  float mn = fmaxf(m_, me);
  float sc = exp2f(m_ - mn), se = exp2f(me - mn);
  l_ = l_ * sc + le * se;
#pragma unroll
  for (int r = 0; r < 16; r++) {
    o0[r] = o0[r] * sc + o_l[r * 64 + lane] * se;
    o1[r] = o1[r] * sc + o_l[(16 + r) * 64 + lane] * se;
  }
  m_ = mn;
}

__device__ __forceinline__ void attn_half(
    const u16* __restrict__ qfb, const u16* __restrict__ kfb,
    const u16* __restrict__ vfb, u16* __restrict__ og,
    float* o_lds, float* ml_lds, bf16x8 ones,
    int qt, int kt0, int w, int lane, int l31, int hi,
    size_t outbase) {
  int qrow = qt * 32 + l31;
  bf16x8 qf[4];
#pragma unroll
  for (int s = 0; s < 4; s++)
    qf[s] = ldb8(qfb + (size_t)qt * 2048 + s * 512 + lane * 8);

  f32x16 o0 = {}, o1 = {}, lsum = {};
  float m_ = -3.0e38f;

#pragma unroll 1
  for (int kt = kt0; kt <= qt; kt += 4)
    attn_step(kfb, vfb, qf, ones, kt, qt, qrow, lane, hi, o0, o1, lsum, m_);

  float l_ = lsum[0];

  if (w >= 2) stash_state(o_lds + (w - 2) * 2048, ml_lds + (w - 2) * 128, lane, o0, o1, m_, l_);
  __syncthreads();
  if (w < 2)  merge_state(o_lds + w * 2048, ml_lds + w * 128, lane, o0, o1, m_, l_);
  __syncthreads();
  if (w == 1) stash_state(o_lds, ml_lds, lane, o0, o1, m_, l_);
  __syncthreads();
  if (w == 0) {
    merge_state(o_lds, ml_lds, lane, o0, o1, m_, l_);
    float inv = 1.0f / l_;
    size_t base = outbase + (size_t)qrow * 1024;
#pragma unroll
    for (int db = 0; db < 2; db++) {
      f32x16 oo = db ? o1 : o0;
#pragma unroll
      for (int r = 0; r < 16; r += 2) {
        int d = db * 32 + (r & 3) + 8 * (r >> 2) + 4 * hi;
        u32 pk_ = cvtpk(oo[r] * inv, oo[r + 1] * inv);
        *reinterpret_cast<u32*>(&og[base + d]) = pk_;
      }
    }
  }
  __syncthreads();
}

__global__ __launch_bounds__(256, 4) void attn_fwd(
    const u16* __restrict__ qg, const u16* __restrict__ kg,
    const u16* __restrict__ vg, u16* __restrict__ og) {
  __shared__ float o_lds[2 * 32 * 64];
  __shared__ float ml_lds[2 * 2 * 64];
  int tid = threadIdx.x, lane = tid & 63, w = tid >> 6;
  int l31 = lane & 31, hi = lane >> 5;
  int blk = blockIdx.x;
  int bh = blk & 63, i = blk >> 6;
  const u16* qfb = qg + (size_t)bh * 131072;
  const u16* kfb = kg + (size_t)bh * 131072;
  const u16* vfb = vg + (size_t)bh * 131072;
  int hh = bh & 15, b = bh >> 4;
  size_t outbase = (size_t)b * 2048 * 1024 + hh * 64;

  u16x8 ov = {0x3F80, 0x3F80, 0x3F80, 0x3F80, 0x3F80, 0x3F80, 0x3F80, 0x3F80};
  bf16x8 ones = __builtin_bit_cast(bf16x8, ov);

  attn_half(qfb, kfb, vfb, og, o_lds, ml_lds, ones, i, w, w, lane, l31, hi, outbase);
  attn_half(qfb, kfb, vfb, og, o_lds, ml_lds, ones, 63 - i, (w - i - 1) & 3, w, lane, l31, hi, outbase);
}

// ---------------- Output GEMM: 256x128 tile, 8 waves, 3-buffer counted-vmcnt ----
// Same template as gemm_qkv + T1 XCD swizzle; fp32 epilogue. Grid (8,32)=256.
__global__ __launch_bounds__(512) void gemm_out(
    const u16* __restrict__ ab, const u16* __restrict__ wb, float* __restrict__ out) {
  __shared__ u16 As[3][256 * 64];   // 96 KB
  __shared__ u16 Bs[3][128 * 64];   // 48 KB
  int tid = threadIdx.x, lane = tid & 63, wid = tid >> 6;
  int wm = wid >> 1, wn = wid & 1;
  int lr = lane & 15, lk = lane >> 4;
  // T1: bijective XCD remap (256 blocks, 256%8==0); same-A-panel on one XCD.
  int orig = blockIdx.x + blockIdx.y * 8;
  int swzb = (orig & 7) * 32 + (orig >> 3);
  int m0 = (swzb >> 3) * 256, n0 = (swzb & 7) * 128;
  const u16* gA = ab + (size_t)m0 * 1024;
  const u16* gB = wb + (size_t)n0 * 1024;
  int swz = lr & 7;

  f32x4 acc[4][4] = {};

#pragma unroll
  for (int rd = 0; rd < 4; rd++) stage_swz(gA, As[0], tid, rd);
#pragma unroll
  for (int rd = 0; rd < 2; rd++) stage_swz(gB, Bs[0], tid, rd);
#pragma unroll
  for (int rd = 0; rd < 4; rd++) stage_swz(gA + 64, As[1], tid, rd);
#pragma unroll
  for (int rd = 0; rd < 2; rd++) stage_swz(gB + 64, Bs[1], tid, rd);
  asm volatile("s_waitcnt vmcnt(6)" ::: "memory");
  __builtin_amdgcn_s_barrier();

#pragma unroll 1
  for (int t = 0; t < 16; t++) {
    const u16* Ac = As[t % 3];
    const u16* Bc = Bs[t % 3];
    u16* An = As[(t + 2) % 3];
    u16* Bn = Bs[(t + 2) % 3];
    const u16* gAn = gA + (t + 2) * 64;
    const u16* gBn = gB + (t + 2) * 64;
    bool pf = (t <= 13);
    bf16x8 af[4], bfr[4];

    // ---- phase 0 ----
#pragma unroll
    for (int mr = 0; mr < 4; mr++)
      af[mr] = ldb8(&Ac[(wm * 64 + mr * 16 + lr) * 64 + ((lk ^ swz) * 8)]);
#pragma unroll
    for (int nr = 0; nr < 4; nr++)
      bfr[nr] = ldb8(&Bc[(wn * 64 + nr * 16 + lr) * 64 + ((lk ^ swz) * 8)]);
    if (pf) {
      stage_swz(gAn, An, tid, 0);
      stage_swz(gAn, An, tid, 1);
      stage_swz(gBn, Bn, tid, 0);
    }
    __builtin_amdgcn_s_setprio(1);
#pragma unroll
    for (int mr = 0; mr < 4; mr++)
#pragma unroll
      for (int nr = 0; nr < 4; nr++)
        acc[mr][nr] = mfma16(af[mr], bfr[nr], acc[mr][nr]);
    __builtin_amdgcn_s_setprio(0);
    __builtin_amdgcn_s_barrier();

    // ---- phase 1 ----
#pragma unroll
    for (int mr = 0; mr < 4; mr++)
      af[mr] = ldb8(&Ac[(wm * 64 + mr * 16 + lr) * 64 + (((lk + 4) ^ swz) * 8)]);
#pragma unroll
    for (int nr = 0; nr < 4; nr++)
      bfr[nr] = ldb8(&Bc[(wn * 64 + nr * 16 + lr) * 64 + (((lk + 4) ^ swz) * 8)]);
    if (pf) {
      stage_swz(gAn, An, tid, 2);
      stage_swz(gAn, An, tid, 3);
      stage_swz(gBn, Bn, tid, 1);
    }
    __builtin_amdgcn_s_setprio(1);
#pragma unroll
    for (int mr = 0; mr < 4; mr++)
#pragma unroll
      for (int nr = 0; nr < 4; nr++)
        acc[mr][nr] = mfma16(af[mr], bfr[nr], acc[mr][nr]);
    __builtin_amdgcn_s_setprio(0);
    if (t < 14) {
      asm volatile("s_waitcnt vmcnt(6)" ::: "memory");
    } else if (t == 14) {
      asm volatile("s_waitcnt vmcnt(0)" ::: "memory");
    }
    __builtin_amdgcn_s_barrier();
  }

  // fp32 epilogue: coalesced dword stores
#pragma unroll
  for (int nr = 0; nr < 4; nr++) {
    int col = n0 + wn * 64 + nr * 16 + lr;
#pragma unroll
    for (int mr = 0; mr < 4; mr++) {
      int Mb = m0 + wm * 64 + mr * 16 + lk * 4;
#pragma unroll
      for (int r = 0; r < 4; r++) {
        out[(size_t)(Mb + r) * 1024 + col] = acc[mr][nr][r];
      }
    }
  }
}

// ---------------- launcher ----------------
extern "C" void kernel_launch(void* const* d_in, const int* in_sizes, int n_in,
                              void* d_out, int out_size, void* d_ws, size_t ws_size,
                              hipStream_t stream) {
  const float* x    = (const float*)d_in[0];
  const float* Wqkv = (const float*)d_in[2];
  const float* Wout = (const float*)d_in[3];
  float* out = (float*)d_out;
  char* ws = (char*)d_ws;

  u16* x_bf    = (u16*)(ws + 0);            // 16 MB
  u16* wqkv_bf = (u16*)(ws + 16777216);     // 6 MB
  u16* wout_bf = (u16*)(ws + 23068672);     // 2 MB
  u16* qf_buf  = (u16*)(ws + 25165824);     // 16 MB  fragment-linear Q (prescaled)
  u16* kf_buf  = (u16*)(ws + 41943040);     // 16 MB  fragment-linear K
  u16* vf_buf  = (u16*)(ws + 58720256);     // 16 MB  fragment-linear V
  u16* a_out   = (u16*)(ws + 75497472);     // 16 MB  (b,t,h*64+d)
  float* cost  = (float*)(ws + 92274688);   // 256 KB
  float* sint  = (float*)(ws + 92536832);   // 256 KB

  prep<<<2048, 256, 0, stream>>>(x, Wqkv, Wout, x_bf, wqkv_bf, wout_bf, cost, sint);
  gemm_qkv<<<dim3(24, 32), 512, 0, stream>>>(x_bf, wqkv_bf, qf_buf, kf_buf, vf_buf, cost, sint);
  attn_fwd<<<2048, 256, 0, stream>>>(qf_buf, kf_buf, vf_buf, a_out);
  gemm_out<<<dim3(8, 32), 512, 0, stream>>>(a_out, wout_bf, out);
}